// Round 10
// baseline (165.385 us; speedup 1.0000x reference)
//
#include <hip/hip_runtime.h>
#include <math.h>

// Problem constants (match reference)
constexpr int Nn   = 8192;
constexpr int Ee   = 4096;
constexpr int DIN  = 256;
constexpr int DOUT = 128;
constexpr int NNZ  = 65536;
constexpr int EC   = 96;   // capacity: nodes per edge (deg ~ Poisson(16))
constexpr int NC   = 48;   // capacity: edges per node (deg ~ Poisson(8))

#define TEMPR 0.08838834764831845f   // 1/sqrt(128)
#define EM1   1.7182818284590452f    // e - 1

// Pair-slot layout: slot s in [0,64) holds dims L(s)=(s>>4)*32+(s&15) and
// H(s)=L(s)+16. All per-dim bf16 rows and fp32 vectors use this layout;
// only k_final's output store unscrambles.
//
// Round-10 theme: rebalance serial-path work.
//  (a) ww3's zero + x-colsum widened 64 -> 128 blocks (was 1 wave/CU on an
//      8 MB cold HBM read -> latency-bound; now 2 waves/CU).
//  (b) vxg/twg redux (needs only degN + x4b) moved from k_nodeB into
//      k_edge1's grid (64 extra blocks); nodeB redux keeps wsg + c2g only.

typedef __attribute__((ext_vector_type(8))) short short8;
typedef __attribute__((ext_vector_type(4))) float f32x4;

static __device__ __forceinline__ float wave_sum64(float v) {
#pragma unroll
    for (int m = 32; m; m >>= 1) v += __shfl_xor(v, m, 64);
    return v;
}
static __device__ __forceinline__ float wave_max64(float v) {
#pragma unroll
    for (int m = 32; m; m >>= 1) v = fmaxf(v, __shfl_xor(v, m, 64));
    return v;
}
static __device__ __forceinline__ short f2bf(float f) {
    union { float f; unsigned u; } v; v.f = f;
    const unsigned r = (v.u + 0x7FFFu + ((v.u >> 16) & 1u)) >> 16;
    return (short)r;
}
static __device__ __forceinline__ unsigned packbf2(float a, float b) {
    return ((unsigned)(unsigned short)f2bf(a)) |
           (((unsigned)(unsigned short)f2bf(b)) << 16);
}
static __device__ __forceinline__ float2 unpackbf2(unsigned u) {
    union { unsigned u; float f; } lo, hi;
    lo.u = u << 16; hi.u = u & 0xFFFF0000u;
    return make_float2(lo.f, hi.f);
}
static __device__ __forceinline__ float bf2f(short s) {
    union { unsigned u; float f; } v;
    v.u = ((unsigned)(unsigned short)s) << 16;
    return v.f;
}

// ---------------------------------------------------------------------------
// K0: prologue. blocks 0..31: WWT; 32..39: W2T; 40: bW3;
//     41..168: zero z-region + per-block x-colsum partials (64 rows each).
// ---------------------------------------------------------------------------
__global__ __launch_bounds__(256) void k_ww3(
    const float* __restrict__ x,
    const float* __restrict__ W, const float* __restrict__ W2,
    const float* __restrict__ W3, const float* __restrict__ bias,
    short* __restrict__ W2T, short* __restrict__ WWT, float* __restrict__ bW3,
    float* __restrict__ sxPart,
    uint4* __restrict__ zb, unsigned zTot16)
{
    __shared__ float sW[8][128];
    __shared__ float sxl[256];
    const int b = blockIdx.x;
    const int t = threadIdx.x;
    if (b < 32) {
        const int r0 = b * 8;
        for (int i = t; i < 1024; i += 256)
            sW[i >> 7][i & 127] = W[(size_t)(r0 + (i >> 7)) * DOUT + (i & 127)];
        __syncthreads();
        const int c  = t & 127;
        const int rh = (t >> 7) * 4;
        float acc[4] = {0.f, 0.f, 0.f, 0.f};
        for (int k = 0; k < 128; ++k) {
            const float w3 = W3[(size_t)k * DOUT + c];
#pragma unroll
            for (int i = 0; i < 4; ++i) acc[i] = fmaf(sW[rh + i][k], w3, acc[i]);
        }
#pragma unroll
        for (int i = 0; i < 4; ++i)
            WWT[(size_t)c * DIN + (r0 + rh + i)] = f2bf(acc[i]);
    } else if (b < 40) {
        const int k0 = (b - 32) * 32;
        for (int i = t; i < 32 * 128; i += 256) {
            const int k = k0 + (i >> 7);
            const int n = i & 127;
            W2T[(size_t)n * DIN + k] = f2bf(W2[(size_t)k * DOUT + n]);
        }
    } else if (b == 40) {
        if (t < 128) {
            float acc = 0.f;
            for (int k = 0; k < 128; ++k)
                acc = fmaf(bias[k], W3[(size_t)k * DOUT + t], acc);
            bW3[t] = acc;
        }
    } else {
        const int zb0 = b - 41;             // 0..127
        uint4 z; z.x = z.y = z.z = z.w = 0u;
        for (unsigned i = (unsigned)zb0 * 256u + t; i < zTot16;
             i += 128u * 256u)
            zb[i] = z;
        // ---- x colsum partial: rows [zb0*64, zb0*64+64) ----
        const int lane = t & 63;
        const int wv   = t >> 6;
        float a0 = 0.f, a1 = 0.f, a2 = 0.f, a3 = 0.f;
#pragma unroll 8
        for (int r = 0; r < 16; ++r) {
            const int row = zb0 * 64 + wv * 16 + r;
            const float4 v = *(const float4*)&x[(size_t)row * DIN + lane * 4];
            a0 += v.x; a1 += v.y; a2 += v.z; a3 += v.w;
        }
        sxl[t] = 0.f;
        __syncthreads();
        atomicAdd(&sxl[lane * 4 + 0], a0);
        atomicAdd(&sxl[lane * 4 + 1], a1);
        atomicAdd(&sxl[lane * 4 + 2], a2);
        atomicAdd(&sxl[lane * 4 + 3], a3);
        __syncthreads();
        sxPart[zb0 * 256 + t] = sxl[t];
    }
}

// ---------------------------------------------------------------------------
// K1: blocks 0..511: MFMA GEMM + CSR build + rowv.
//     block 512: reduce sxPart -> sx; matvecs -> csx4/csxw (slot layout).
// ---------------------------------------------------------------------------
__global__ __launch_bounds__(256) void k_gemm1f(
    const float* __restrict__ x, const short* __restrict__ W2T,
    const short* __restrict__ WWT, const float* __restrict__ bW3,
    const float* __restrict__ q, const int* __restrict__ hidx,
    const float* __restrict__ sxPart,
    unsigned* __restrict__ bitmap, int* __restrict__ degE, int* __restrict__ degN,
    int* __restrict__ csrEn, int* __restrict__ csrNe, int* __restrict__ csrNs,
    unsigned* __restrict__ x4b, unsigned* __restrict__ xwb,
    float* __restrict__ rowv, float* __restrict__ csx4, float* __restrict__ csxw)
{
    __shared__ float srow[16];
    __shared__ float sxv[256];
    const int t = threadIdx.x;

    if (blockIdx.x == 512) {
        // ---- analytic colsums: csx4 = sx@W2T(bf16), csxw = sx@WWT + Nn*bW3
        float s = 0.f;
        for (int b2 = 0; b2 < 128; ++b2) s += sxPart[b2 * 256 + t];
        sxv[t] = s;
        __syncthreads();
        const int c  = t & 127;
        const int g  = c >> 5, r = c & 31;
        const int pos = 2 * (g * 16 + (r & 15)) + (r >> 4);   // slot layout
        if (t < 128) {
            float acc = 0.f;
            for (int k = 0; k < 256; ++k)
                acc = fmaf(sxv[k], bf2f(W2T[(size_t)c * DIN + k]), acc);
            csx4[pos] = acc;
        } else {
            float acc = 0.f;
            for (int k = 0; k < 256; ++k)
                acc = fmaf(sxv[k], bf2f(WWT[(size_t)c * DIN + k]), acc);
            csxw[pos] = acc + (float)Nn * bW3[c];
        }
        return;
    }

    const int lane = t & 63;
    const int wv   = t >> 6;
    const int n16  = lane & 15;
    const int quad = lane >> 4;
    const int r0   = blockIdx.x * 16;
    const int n0   = wv * 32;

    // ---- CSR build ----
    const unsigned gid = blockIdx.x * 256 + t;
    if (gid < NNZ) {
        const int n = hidx[gid];
        const int e = hidx[NNZ + gid];
        const unsigned word = (unsigned)n * (unsigned)Ee + (unsigned)e;
        const unsigned bit  = 1u << (word & 31u);
        const unsigned old  = atomicOr(&bitmap[word >> 5], bit);
        if (!(old & bit)) {
            const int pe = atomicAdd(&degE[e], 1);
            if (pe < EC) {
                csrEn[e * EC + pe] = n;
                const int pn = atomicAdd(&degN[n], 1);
                if (pn < NC) {
                    csrNe[n * NC + pn] = e;
                    csrNs[n * NC + pn] = e * EC + pe;
                }
            }
        }
    }

    // ---- MFMA main loop ----
    f32x4 acc4[2], accw[2];
#pragma unroll
    for (int nt = 0; nt < 2; ++nt) {
        acc4[nt] = (f32x4){0.f, 0.f, 0.f, 0.f};
        accw[nt] = (f32x4){0.f, 0.f, 0.f, 0.f};
    }
#pragma unroll
    for (int k0 = 0; k0 < DIN; k0 += 32) {
        const int kb = k0 + quad * 8;
        const float4 xa = *(const float4*)&x[(size_t)(r0 + n16) * DIN + kb];
        const float4 xb = *(const float4*)&x[(size_t)(r0 + n16) * DIN + kb + 4];
        short8 af;
        af[0] = f2bf(xa.x); af[1] = f2bf(xa.y); af[2] = f2bf(xa.z); af[3] = f2bf(xa.w);
        af[4] = f2bf(xb.x); af[5] = f2bf(xb.y); af[6] = f2bf(xb.z); af[7] = f2bf(xb.w);
#pragma unroll
        for (int nt = 0; nt < 2; ++nt) {
            const int col = n0 + nt * 16 + n16;
            const short8 b4 = *(const short8*)&W2T[(size_t)col * DIN + kb];
            const short8 bw = *(const short8*)&WWT[(size_t)col * DIN + kb];
            acc4[nt] = __builtin_amdgcn_mfma_f32_16x16x32_bf16(af, b4, acc4[nt], 0, 0, 0);
            accw[nt] = __builtin_amdgcn_mfma_f32_16x16x32_bf16(af, bw, accw[nt], 0, 0, 0);
        }
    }

    // ---- writeback (slot layout, paired dword stores) + rowv epilogue ----
    float bwv[2], qv[2];
#pragma unroll
    for (int nt = 0; nt < 2; ++nt) {
        const int col = n0 + nt * 16 + n16;
        bwv[nt] = bW3[col];
        qv[nt]  = q[col];
    }
    const int s = wv * 16 + n16;   // pair-slot: cols (n0+n16, n0+16+n16)
#pragma unroll
    for (int reg = 0; reg < 4; ++reg) {
        const int row = r0 + quad * 4 + reg;
        x4b[(size_t)row * 64 + s] = packbf2(acc4[0][reg], acc4[1][reg]);
        xwb[(size_t)row * 64 + s] = packbf2(accw[0][reg] + bwv[0],
                                            accw[1][reg] + bwv[1]);
    }
    float pr[4];
#pragma unroll
    for (int reg = 0; reg < 4; ++reg)
        pr[reg] = qv[0] * acc4[0][reg] + qv[1] * acc4[1][reg];
#pragma unroll
    for (int m = 8; m; m >>= 1) {
#pragma unroll
        for (int reg = 0; reg < 4; ++reg) pr[reg] += __shfl_xor(pr[reg], m, 64);
    }
    if (t < 16) srow[t] = 0.f;
    __syncthreads();
    if (n16 == 0) {
#pragma unroll
        for (int reg = 0; reg < 4; ++reg) atomicAdd(&srow[quad * 4 + reg], pr[reg]);
    }
    __syncthreads();
    if (t < 16) rowv[r0 + t] = srow[t] * TEMPR;
}

// ---------------------------------------------------------------------------
// K2: blocks 0..Ee/2-1: per-edge softmax1 -> Sval + ws scatter; gathers
//     e4b / G1b. Blocks Ee/2..: vxg/twg redux (moved from k_nodeB — needs
//     only degN + x4b, both ready after K1).
// ---------------------------------------------------------------------------
__global__ __launch_bounds__(128, 4) void k_edge1(
    const int* __restrict__ degE, const int* __restrict__ degN,
    const int* __restrict__ csrEn,
    const float* __restrict__ rowv,
    const float* __restrict__ csx4, const float* __restrict__ csxw,
    const unsigned* __restrict__ x4b, const unsigned* __restrict__ xwb,
    float* __restrict__ Sval, unsigned* __restrict__ e4b, unsigned* __restrict__ G1b,
    float* __restrict__ wsArr, float* __restrict__ vxg, float* __restrict__ twg)
{
    __shared__ int   sN[2][EC];
    __shared__ float sS[2][EC];
    const int t    = threadIdx.x;
    const int w    = t >> 6;
    const int lane = t & 63;

    if (blockIdx.x >= Ee / 2) {           // ---- vxg/twg redux part ----
        const int rb = blockIdx.x - Ee / 2;   // 0..63, 128 nodes each
        float2 av = {0.f, 0.f}, at2 = {0.f, 0.f};
        for (int k = 0; k < 64; ++k) {
            const int n   = rb * 128 + w + k * 2;
            const int dg  = min(degN[n], NC);
            const float vn = dg ? 1.0f / ((float)Ee + (float)dg * EM1)
                                : 2.0f / (float)Ee;
            const float tw = dg ? fmaf((float)dg * EM1, vn, 1.0f) : 0.f;
            const float2 xv = unpackbf2(x4b[(size_t)n * 64 + lane]);
            av.x  = fmaf(vn, xv.x, av.x);  av.y  = fmaf(vn, xv.y, av.y);
            at2.x = fmaf(tw, xv.x, at2.x); at2.y = fmaf(tw, xv.y, at2.y);
        }
        atomicAdd(&vxg[lane*2+0], av.x);  atomicAdd(&vxg[lane*2+1], av.y);
        atomicAdd(&twg[lane*2+0], at2.x); atomicAdd(&twg[lane*2+1], at2.y);
        return;
    }

    const int e    = blockIdx.x * 2 + w;
    const int deg  = min(degE[e], EC);
    const float ue = deg ? 1.0f / ((float)Nn + (float)deg * EM1) : 2.0f / (float)Nn;

    int   n0 = 0, n1 = 0;
    float r0 = -INFINITY, r1 = -INFINITY;
    if (lane < deg)      { n0 = csrEn[e * EC + lane];      r0 = rowv[n0]; }
    if (lane + 64 < deg) { n1 = csrEn[e * EC + lane + 64]; r1 = rowv[n1]; }
    const float m  = wave_max64(fmaxf(r0, r1));
    const float e0 = (lane < deg)      ? expf(r0 - m) : 0.f;
    const float e1 = (lane + 64 < deg) ? expf(r1 - m) : 0.f;
    const float Z  = wave_sum64(e0 + e1);
    const float inv = deg ? 1.0f / Z : 0.f;
    const float base = EM1 * ue;
    if (lane < deg) {
        const float sv = fmaf(e0, inv, base);
        sN[w][lane] = n0; sS[w][lane] = sv;
        Sval[e * EC + lane] = sv;
        atomicAdd(&wsArr[n0], ue * sv);
    }
    if (lane + 64 < deg) {
        const float sv = fmaf(e1, inv, base);
        sN[w][lane + 64] = n1; sS[w][lane + 64] = sv;
        Sval[e * EC + lane + 64] = sv;
        atomicAdd(&wsArr[n1], ue * sv);
    }

    const float2 cw = *(const float2*)&csxw[lane * 2];
    const float2 c4 = *(const float2*)&csx4[lane * 2];
    float2 aE = make_float2(ue * cw.x, ue * cw.y);
    float2 aG = make_float2(ue * c4.x, ue * c4.y);
    int j = 0;
    for (; j + 16 <= deg; j += 16) {
        int ai[16]; float bi[16]; unsigned tu[16], fu[16];
#pragma unroll
        for (int k = 0; k < 16; ++k) { ai[k] = sN[w][j+k]; bi[k] = sS[w][j+k]; }
#pragma unroll
        for (int k = 0; k < 16; ++k) {
            tu[k] = xwb[(size_t)ai[k] * 64 + lane];
            fu[k] = x4b[(size_t)ai[k] * 64 + lane];
        }
#pragma unroll
        for (int k = 0; k < 16; ++k) {
            const float2 tv = unpackbf2(tu[k]);
            const float2 fv = unpackbf2(fu[k]);
            aE.x = fmaf(bi[k], tv.x, aE.x); aE.y = fmaf(bi[k], tv.y, aE.y);
            aG.x = fmaf(bi[k], fv.x, aG.x); aG.y = fmaf(bi[k], fv.y, aG.y);
        }
    }
    for (; j + 8 <= deg; j += 8) {
        int ai[8]; float bi[8]; unsigned tu[8], fu[8];
#pragma unroll
        for (int k = 0; k < 8; ++k) { ai[k] = sN[w][j+k]; bi[k] = sS[w][j+k]; }
#pragma unroll
        for (int k = 0; k < 8; ++k) {
            tu[k] = xwb[(size_t)ai[k] * 64 + lane];
            fu[k] = x4b[(size_t)ai[k] * 64 + lane];
        }
#pragma unroll
        for (int k = 0; k < 8; ++k) {
            const float2 tv = unpackbf2(tu[k]);
            const float2 fv = unpackbf2(fu[k]);
            aE.x = fmaf(bi[k], tv.x, aE.x); aE.y = fmaf(bi[k], tv.y, aE.y);
            aG.x = fmaf(bi[k], fv.x, aG.x); aG.y = fmaf(bi[k], fv.y, aG.y);
        }
    }
    for (; j < deg; ++j) {
        const int   a = sN[w][j];
        const float b = sS[w][j];
        const float2 tv = unpackbf2(xwb[(size_t)a * 64 + lane]);
        const float2 fv = unpackbf2(x4b[(size_t)a * 64 + lane]);
        aE.x = fmaf(b, tv.x, aE.x); aE.y = fmaf(b, tv.y, aE.y);
        aG.x = fmaf(b, fv.x, aG.x); aG.y = fmaf(b, fv.y, aG.y);
    }
    e4b[(size_t)e * 64 + lane] = packbf2(aE.x, aE.y);
    G1b[(size_t)e * 64 + lane] = packbf2(aG.x, aG.y);
}

// ---------------------------------------------------------------------------
// K3: merged. Blocks 0..63: wsg colsum + c2g. Blocks 64..: per-node
//     softmax2 (one node/wave, 8 edge-slots x 8 dim-lanes) -> Tval.
// ---------------------------------------------------------------------------
__global__ __launch_bounds__(256) void k_nodeB(
    const int* __restrict__ degN, const int* __restrict__ degE,
    const int* __restrict__ csrNe,
    const int* __restrict__ csrNs, const unsigned* __restrict__ x4b,
    const unsigned* __restrict__ e4b, const float* __restrict__ wsArr,
    float* __restrict__ Tval,
    float* __restrict__ wsg, float* __restrict__ c2g)
{
    const int t    = threadIdx.x;
    const int w    = t >> 6;
    const int lane = t & 63;
    const int b    = blockIdx.x;

    if (b < 64) {                         // ---- redux part (wsg + c2g) ----
        float2 aw = {0.f, 0.f};
        for (int k = 0; k < 32; ++k) {
            const int n   = b * 128 + w + k * 4;
            const float wsn = wsArr[n];
            const float2 xv = unpackbf2(x4b[(size_t)n * 64 + lane]);
            aw.x = fmaf(wsn, xv.x, aw.x); aw.y = fmaf(wsn, xv.y, aw.y);
        }
        atomicAdd(&wsg[lane*2+0], aw.x); atomicAdd(&wsg[lane*2+1], aw.y);
        const int gid = b * 256 + t;
        if (gid < Ee) {
            const int de = min(degE[gid], EC);
            const float ue = de ? 1.0f / ((float)Nn + (float)de * EM1)
                                : 2.0f / (float)Nn;
            const float v = wave_sum64(ue * ue);
            if (lane == 0) atomicAdd(c2g, v);
        }
        return;
    }

    // ---- node2 part ----
    const int es   = lane >> 3;           // edge slot within pass (0..7)
    const int dl   = lane & 7;            // dim-lane
    const int n    = (b - 64) * 4 + w;    // one node per wave
    const int deg  = min(degN[n], NC);
    if (!deg) return;                     // wave-uniform
    const float vn = 1.0f / ((float)Ee + (float)deg * EM1);

    const uint4* xr = (const uint4*)&x4b[(size_t)n * 64];
    const uint4 xua = xr[dl * 2], xub = xr[dl * 2 + 1];
    const float2 x0 = unpackbf2(xua.x), x1 = unpackbf2(xua.y),
                 x2 = unpackbf2(xua.z), x3 = unpackbf2(xua.w),
                 x4v = unpackbf2(xub.x), x5 = unpackbf2(xub.y),
                 x6 = unpackbf2(xub.z), x7 = unpackbf2(xub.w);

    float dps[6]; float exs[6]; int slots[6];
    float m = -INFINITY;
#pragma unroll
    for (int p = 0; p < 6; ++p) {
        dps[p] = -INFINITY; slots[p] = 0;
        if (p * 8 >= deg) continue;       // wave-uniform branch
        const int j = p * 8 + es;
        int ej = 0;
        if (j < deg) { ej = csrNe[n * NC + j]; slots[p] = csrNs[n * NC + j]; }
        const uint4* er = (const uint4*)&e4b[(size_t)ej * 64];
        const uint4 ea = er[dl * 2], eb = er[dl * 2 + 1];
        float d0 = 0.f, d1 = 0.f, d2 = 0.f, d3 = 0.f;
        { const float2 ev = unpackbf2(ea.x); d0 = fmaf(ev.x, x0.x, d0); d0 = fmaf(ev.y, x0.y, d0); }
        { const float2 ev = unpackbf2(ea.y); d1 = fmaf(ev.x, x1.x, d1); d1 = fmaf(ev.y, x1.y, d1); }
        { const float2 ev = unpackbf2(ea.z); d2 = fmaf(ev.x, x2.x, d2); d2 = fmaf(ev.y, x2.y, d2); }
        { const float2 ev = unpackbf2(ea.w); d3 = fmaf(ev.x, x3.x, d3); d3 = fmaf(ev.y, x3.y, d3); }
        { const float2 ev = unpackbf2(eb.x); d0 = fmaf(ev.x, x4v.x, d0); d0 = fmaf(ev.y, x4v.y, d0); }
        { const float2 ev = unpackbf2(eb.y); d1 = fmaf(ev.x, x5.x, d1); d1 = fmaf(ev.y, x5.y, d1); }
        { const float2 ev = unpackbf2(eb.z); d2 = fmaf(ev.x, x6.x, d2); d2 = fmaf(ev.y, x6.y, d2); }
        { const float2 ev = unpackbf2(eb.w); d3 = fmaf(ev.x, x7.x, d3); d3 = fmaf(ev.y, x7.y, d3); }
        float dot = (d0 + d1) + (d2 + d3);
        dot += __shfl_xor(dot, 1, 64);
        dot += __shfl_xor(dot, 2, 64);
        dot += __shfl_xor(dot, 4, 64);
        dot = (j < deg) ? dot * TEMPR : -INFINITY;
        dps[p] = dot;
        float mm = fmaxf(dot, __shfl_xor(dot, 8, 64));
        mm = fmaxf(mm, __shfl_xor(mm, 16, 64));
        mm = fmaxf(mm, __shfl_xor(mm, 32, 64));
        m = fmaxf(m, mm);
    }
    float Z = 0.f;
#pragma unroll
    for (int p = 0; p < 6; ++p) {
        exs[p] = 0.f;
        if (p * 8 >= deg) continue;
        const float ex = (p * 8 + es < deg) ? expf(dps[p] - m) : 0.f;
        exs[p] = ex;
        float sum = ex + __shfl_xor(ex, 8, 64);
        sum += __shfl_xor(sum, 16, 64);
        sum += __shfl_xor(sum, 32, 64);
        Z += sum;
    }
    const float invZ = 1.0f / Z;
#pragma unroll
    for (int p = 0; p < 6; ++p) {
        if (p * 8 >= deg) continue;
        if (dl == 0 && p * 8 + es < deg)
            Tval[slots[p]] = fmaf(EM1, vn, exs[p] * invZ);
    }
}

// ---------------------------------------------------------------------------
// K4: per-edge: G2b[e] = vx + sum_{n in e} T[e,n] * x4[n].
// ---------------------------------------------------------------------------
__global__ __launch_bounds__(128, 4) void k_g2(
    const int* __restrict__ degE, const int* __restrict__ csrEn,
    const float* __restrict__ Tval, const float* __restrict__ vxg,
    const unsigned* __restrict__ x4b, unsigned* __restrict__ G2b)
{
    const int t    = threadIdx.x;
    const int w    = t >> 6;
    const int lane = t & 63;
    const int e    = blockIdx.x * 2 + w;
    const int deg  = min(degE[e], EC);
    float2 acc = *(const float2*)&vxg[lane * 2];
    int j = 0;
    for (; j + 16 <= deg; j += 16) {
        int ai[16]; float bi[16]; unsigned fu[16];
#pragma unroll
        for (int k = 0; k < 16; ++k) { ai[k] = csrEn[e*EC+j+k]; bi[k] = Tval[e*EC+j+k]; }
#pragma unroll
        for (int k = 0; k < 16; ++k)
            fu[k] = x4b[(size_t)ai[k] * 64 + lane];
#pragma unroll
        for (int k = 0; k < 16; ++k) {
            const float2 fv = unpackbf2(fu[k]);
            acc.x = fmaf(bi[k], fv.x, acc.x); acc.y = fmaf(bi[k], fv.y, acc.y);
        }
    }
    for (; j + 8 <= deg; j += 8) {
        int ai[8]; float bi[8]; unsigned fu[8];
#pragma unroll
        for (int k = 0; k < 8; ++k) { ai[k] = csrEn[e*EC+j+k]; bi[k] = Tval[e*EC+j+k]; }
#pragma unroll
        for (int k = 0; k < 8; ++k)
            fu[k] = x4b[(size_t)ai[k] * 64 + lane];
#pragma unroll
        for (int k = 0; k < 8; ++k) {
            const float2 fv = unpackbf2(fu[k]);
            acc.x = fmaf(bi[k], fv.x, acc.x); acc.y = fmaf(bi[k], fv.y, acc.y);
        }
    }
    for (; j < deg; ++j) {
        const int   a = csrEn[e*EC+j];
        const float b = Tval[e*EC+j];
        const float2 fv = unpackbf2(x4b[(size_t)a * 64 + lane]);
        acc.x = fmaf(b, fv.x, acc.x); acc.y = fmaf(b, fv.y, acc.y);
    }
    G2b[(size_t)e * 64 + lane] = packbf2(acc.x, acc.y);
}

// ---------------------------------------------------------------------------
// K5: final per-node combine + elu.  Unscrambles slot layout.
// ---------------------------------------------------------------------------
__global__ __launch_bounds__(128, 4) void k_final(
    const int* __restrict__ degN, const int* __restrict__ csrNe,
    const int* __restrict__ csrNs, const float* __restrict__ Sval,
    const float* __restrict__ Tval,
    const float* __restrict__ c2g, const float* __restrict__ csx4,
    const float* __restrict__ wsg, const float* __restrict__ vxg,
    const float* __restrict__ twg,
    const unsigned* __restrict__ G1b, const unsigned* __restrict__ G2b,
    float* __restrict__ out)
{
    const int t    = threadIdx.x;
    const int w    = t >> 6;
    const int lane = t & 63;
    const int n    = blockIdx.x * 2 + w;
    const int deg  = min(degN[n], NC);
    const float vn = deg ? 1.0f / ((float)Ee + (float)deg * EM1) : 2.0f / (float)Ee;
    const float c2 = *c2g;
    const float2 c4v = *(const float2*)&csx4[lane * 2];
    const float2 wsv = *(const float2*)&wsg[lane * 2];
    const float2 vxv = *(const float2*)&vxg[lane * 2];
    const float2 twv = *(const float2*)&twg[lane * 2];
    float2 acc;
    acc.x = fmaf(c2, c4v.x, wsv.x) + vn * fmaf((float)Ee, vxv.x, twv.x);
    acc.y = fmaf(c2, c4v.y, wsv.y) + vn * fmaf((float)Ee, vxv.y, twv.y);
    int j = 0;
    for (; j + 8 <= deg; j += 8) {
        int ei[8], si[8]; float sv[8], tv[8]; unsigned g1u[8], g2u[8];
#pragma unroll
        for (int k = 0; k < 8; ++k) {
            ei[k] = csrNe[n*NC+j+k]; si[k] = csrNs[n*NC+j+k];
        }
#pragma unroll
        for (int k = 0; k < 8; ++k) {
            sv[k] = Sval[si[k]]; tv[k] = Tval[si[k]];
            g1u[k] = G1b[(size_t)ei[k] * 64 + lane];
            g2u[k] = G2b[(size_t)ei[k] * 64 + lane];
        }
#pragma unroll
        for (int k = 0; k < 8; ++k) {
            const float2 g1 = unpackbf2(g1u[k]);
            const float2 g2 = unpackbf2(g2u[k]);
            acc.x = fmaf(sv[k], g1.x, acc.x); acc.y = fmaf(sv[k], g1.y, acc.y);
            acc.x = fmaf(tv[k], g2.x, acc.x); acc.y = fmaf(tv[k], g2.y, acc.y);
        }
    }
    for (; j + 4 <= deg; j += 4) {
        int ei[4], si[4]; float sv[4], tv[4]; unsigned g1u[4], g2u[4];
#pragma unroll
        for (int k = 0; k < 4; ++k) {
            ei[k] = csrNe[n*NC+j+k]; si[k] = csrNs[n*NC+j+k];
        }
#pragma unroll
        for (int k = 0; k < 4; ++k) {
            sv[k] = Sval[si[k]]; tv[k] = Tval[si[k]];
            g1u[k] = G1b[(size_t)ei[k] * 64 + lane];
            g2u[k] = G2b[(size_t)ei[k] * 64 + lane];
        }
#pragma unroll
        for (int k = 0; k < 4; ++k) {
            const float2 g1 = unpackbf2(g1u[k]);
            const float2 g2 = unpackbf2(g2u[k]);
            acc.x = fmaf(sv[k], g1.x, acc.x); acc.y = fmaf(sv[k], g1.y, acc.y);
            acc.x = fmaf(tv[k], g2.x, acc.x); acc.y = fmaf(tv[k], g2.y, acc.y);
        }
    }
    for (; j < deg; ++j) {
        const int ea = csrNe[n*NC+j];
        const int sa = csrNs[n*NC+j];
        const float sva = Sval[sa], tva = Tval[sa];
        const float2 g1a = unpackbf2(G1b[(size_t)ea * 64 + lane]);
        const float2 g2a = unpackbf2(G2b[(size_t)ea * 64 + lane]);
        acc.x = fmaf(sva, g1a.x, acc.x); acc.y = fmaf(sva, g1a.y, acc.y);
        acc.x = fmaf(tva, g2a.x, acc.x); acc.y = fmaf(tva, g2a.y, acc.y);
    }
    acc.x = acc.x > 0.f ? acc.x : expm1f(acc.x);
    acc.y = acc.y > 0.f ? acc.y : expm1f(acc.y);
    // unscramble slot layout: slot holds dims lo and lo+16
    const int lo = ((lane >> 4) << 5) + (lane & 15);
    out[(size_t)n * DOUT + lo]      = acc.x;
    out[(size_t)n * DOUT + lo + 16] = acc.y;
}

// ---------------------------------------------------------------------------
extern "C" void kernel_launch(void* const* d_in, const int* in_sizes, int n_in,
                              void* d_out, int out_size, void* d_ws, size_t ws_size,
                              hipStream_t stream)
{
    const float* x    = (const float*)d_in[0];
    const float* W    = (const float*)d_in[1];
    const float* W2   = (const float*)d_in[2];
    const float* W3   = (const float*)d_in[3];
    const float* bias = (const float*)d_in[4];
    const float* q    = (const float*)d_in[5];
    const int*   hidx = (const int*)d_in[6];
    float* out = (float*)d_out;

    char* wsp = (char*)d_ws;
    size_t o = 0;
    auto take = [&](size_t bytes) {
        size_t r = o; o += (bytes + 255) & ~(size_t)255; return r;
    };
    // --- zero-initialized region (zeroed by k_ww3 blocks 41..168) ---
    unsigned* bitmap = (unsigned*)(wsp + take((size_t)Nn * Ee / 8));   // 4 MB
    int*   degE  = (int*)  (wsp + take((size_t)Ee * 4));
    int*   degN  = (int*)  (wsp + take((size_t)Nn * 4));
    float* wsArr = (float*)(wsp + take((size_t)Nn * 4));
    float* c2g   = (float*)(wsp + take(4));
    float* vxg   = (float*)(wsp + take(DOUT * 4));
    float* twg   = (float*)(wsp + take(DOUT * 4));
    float* wsg   = (float*)(wsp + take(DOUT * 4));
    const size_t zbytes = o;
    // --- fully-overwritten scratch ---
    float*    csx4  = (float*)   (wsp + take(DOUT * 4));
    float*    csxw  = (float*)   (wsp + take(DOUT * 4));
    float*    sxPart= (float*)   (wsp + take(128 * 256 * 4));         // 128 KB
    unsigned* x4b   = (unsigned*)(wsp + take((size_t)Nn * 64 * 4));   // bf16 pairs
    unsigned* xwb   = (unsigned*)(wsp + take((size_t)Nn * 64 * 4));   // bf16 pairs
    float*    rowv  = (float*)   (wsp + take((size_t)Nn * 4));
    int*      csrEn = (int*)     (wsp + take((size_t)Ee * EC * 4));
    float*    Sval  = (float*)   (wsp + take((size_t)Ee * EC * 4));
    float*    Tval  = (float*)   (wsp + take((size_t)Ee * EC * 4));
    int*      csrNe = (int*)     (wsp + take((size_t)Nn * NC * 4));
    int*      csrNs = (int*)     (wsp + take((size_t)Nn * NC * 4));
    unsigned* e4b   = (unsigned*)(wsp + take((size_t)Ee * 64 * 4));   // bf16 pairs
    unsigned* G1b   = (unsigned*)(wsp + take((size_t)Ee * 64 * 4));   // bf16 pairs
    unsigned* G2b   = (unsigned*)(wsp + take((size_t)Ee * 64 * 4));   // bf16 pairs
    short*    W2T   = (short*)   (wsp + take((size_t)DOUT * DIN * 2));
    short*    WWT   = (short*)   (wsp + take((size_t)DOUT * DIN * 2));
    float*    bW3   = (float*)   (wsp + take(DOUT * 4));
    (void)ws_size; (void)in_sizes; (void)n_in; (void)out_size;

    k_ww3   <<<169,          256, 0, stream>>>(x, W, W2, W3, bias, W2T, WWT, bW3,
                                               sxPart, (uint4*)d_ws,
                                               (unsigned)(zbytes / 16));
    k_gemm1f<<<513,          256, 0, stream>>>(x, W2T, WWT, bW3, q, hidx, sxPart,
                                               bitmap, degE, degN, csrEn, csrNe,
                                               csrNs, x4b, xwb, rowv, csx4, csxw);
    k_edge1 <<<Ee / 2 + 64,  128, 0, stream>>>(degE, degN, csrEn, rowv, csx4, csxw,
                                               x4b, xwb, Sval, e4b, G1b, wsArr,
                                               vxg, twg);
    k_nodeB <<<64 + Nn / 4,  256, 0, stream>>>(degN, degE, csrNe, csrNs, x4b, e4b,
                                               wsArr, Tval, wsg, c2g);
    k_g2    <<<Ee / 2,       128, 0, stream>>>(degE, csrEn, Tval, vxg, x4b, G2b);
    k_final <<<Nn / 2,       128, 0, stream>>>(degN, csrNe, csrNs, Sval, Tval,
                                               c2g, csx4, wsg, vxg, twg, G1b, G2b,
                                               out);
}

// Round 11
// 155.537 us; speedup vs baseline: 1.0633x; 1.0633x over previous
//
#include <hip/hip_runtime.h>
#include <math.h>

// Problem constants (match reference)
constexpr int Nn   = 8192;
constexpr int Ee   = 4096;
constexpr int DIN  = 256;
constexpr int DOUT = 128;
constexpr int NNZ  = 65536;
constexpr int EC   = 96;   // capacity: nodes per edge (deg ~ Poisson(16))
constexpr int NC   = 48;   // capacity: edges per node (deg ~ Poisson(8))

#define TEMPR 0.08838834764831845f   // 1/sqrt(128)
#define EM1   1.7182818284590452f    // e - 1

// Pair-slot layout: slot s in [0,64) holds dims L(s)=(s>>4)*32+(s&15) and
// H(s)=L(s)+16. All per-dim bf16 rows and fp32 vectors use this layout;
// only k_final's output store unscrambles.
//
// Round-11: disentangle round-10's bundle. KEEP (a): ww3 zero+colsum at
// 128 blocks (2 waves/CU on the 8 MB x read). REVERT (b): vxg/twg redux
// back into k_nodeB (round-9 structure) — the edge1-tail redux blocks
// were the suspected straggler regression.

typedef __attribute__((ext_vector_type(8))) short short8;
typedef __attribute__((ext_vector_type(4))) float f32x4;

static __device__ __forceinline__ float wave_sum64(float v) {
#pragma unroll
    for (int m = 32; m; m >>= 1) v += __shfl_xor(v, m, 64);
    return v;
}
static __device__ __forceinline__ float wave_max64(float v) {
#pragma unroll
    for (int m = 32; m; m >>= 1) v = fmaxf(v, __shfl_xor(v, m, 64));
    return v;
}
static __device__ __forceinline__ short f2bf(float f) {
    union { float f; unsigned u; } v; v.f = f;
    const unsigned r = (v.u + 0x7FFFu + ((v.u >> 16) & 1u)) >> 16;
    return (short)r;
}
static __device__ __forceinline__ unsigned packbf2(float a, float b) {
    return ((unsigned)(unsigned short)f2bf(a)) |
           (((unsigned)(unsigned short)f2bf(b)) << 16);
}
static __device__ __forceinline__ float2 unpackbf2(unsigned u) {
    union { unsigned u; float f; } lo, hi;
    lo.u = u << 16; hi.u = u & 0xFFFF0000u;
    return make_float2(lo.f, hi.f);
}
static __device__ __forceinline__ float bf2f(short s) {
    union { unsigned u; float f; } v;
    v.u = ((unsigned)(unsigned short)s) << 16;
    return v.f;
}

// ---------------------------------------------------------------------------
// K0: prologue. blocks 0..31: WWT; 32..39: W2T; 40: bW3;
//     41..168: zero z-region + per-block x-colsum partials (64 rows each).
// ---------------------------------------------------------------------------
__global__ __launch_bounds__(256) void k_ww3(
    const float* __restrict__ x,
    const float* __restrict__ W, const float* __restrict__ W2,
    const float* __restrict__ W3, const float* __restrict__ bias,
    short* __restrict__ W2T, short* __restrict__ WWT, float* __restrict__ bW3,
    float* __restrict__ sxPart,
    uint4* __restrict__ zb, unsigned zTot16)
{
    __shared__ float sW[8][128];
    __shared__ float sxl[256];
    const int b = blockIdx.x;
    const int t = threadIdx.x;
    if (b < 32) {
        const int r0 = b * 8;
        for (int i = t; i < 1024; i += 256)
            sW[i >> 7][i & 127] = W[(size_t)(r0 + (i >> 7)) * DOUT + (i & 127)];
        __syncthreads();
        const int c  = t & 127;
        const int rh = (t >> 7) * 4;
        float acc[4] = {0.f, 0.f, 0.f, 0.f};
        for (int k = 0; k < 128; ++k) {
            const float w3 = W3[(size_t)k * DOUT + c];
#pragma unroll
            for (int i = 0; i < 4; ++i) acc[i] = fmaf(sW[rh + i][k], w3, acc[i]);
        }
#pragma unroll
        for (int i = 0; i < 4; ++i)
            WWT[(size_t)c * DIN + (r0 + rh + i)] = f2bf(acc[i]);
    } else if (b < 40) {
        const int k0 = (b - 32) * 32;
        for (int i = t; i < 32 * 128; i += 256) {
            const int k = k0 + (i >> 7);
            const int n = i & 127;
            W2T[(size_t)n * DIN + k] = f2bf(W2[(size_t)k * DOUT + n]);
        }
    } else if (b == 40) {
        if (t < 128) {
            float acc = 0.f;
            for (int k = 0; k < 128; ++k)
                acc = fmaf(bias[k], W3[(size_t)k * DOUT + t], acc);
            bW3[t] = acc;
        }
    } else {
        const int zb0 = b - 41;             // 0..127
        uint4 z; z.x = z.y = z.z = z.w = 0u;
        for (unsigned i = (unsigned)zb0 * 256u + t; i < zTot16;
             i += 128u * 256u)
            zb[i] = z;
        // ---- x colsum partial: rows [zb0*64, zb0*64+64) ----
        const int lane = t & 63;
        const int wv   = t >> 6;
        float a0 = 0.f, a1 = 0.f, a2 = 0.f, a3 = 0.f;
#pragma unroll 8
        for (int r = 0; r < 16; ++r) {
            const int row = zb0 * 64 + wv * 16 + r;
            const float4 v = *(const float4*)&x[(size_t)row * DIN + lane * 4];
            a0 += v.x; a1 += v.y; a2 += v.z; a3 += v.w;
        }
        sxl[t] = 0.f;
        __syncthreads();
        atomicAdd(&sxl[lane * 4 + 0], a0);
        atomicAdd(&sxl[lane * 4 + 1], a1);
        atomicAdd(&sxl[lane * 4 + 2], a2);
        atomicAdd(&sxl[lane * 4 + 3], a3);
        __syncthreads();
        sxPart[zb0 * 256 + t] = sxl[t];
    }
}

// ---------------------------------------------------------------------------
// K1: blocks 0..511: MFMA GEMM + CSR build + rowv.
//     block 512: reduce sxPart -> sx; matvecs -> csx4/csxw (slot layout).
// ---------------------------------------------------------------------------
__global__ __launch_bounds__(256) void k_gemm1f(
    const float* __restrict__ x, const short* __restrict__ W2T,
    const short* __restrict__ WWT, const float* __restrict__ bW3,
    const float* __restrict__ q, const int* __restrict__ hidx,
    const float* __restrict__ sxPart,
    unsigned* __restrict__ bitmap, int* __restrict__ degE, int* __restrict__ degN,
    int* __restrict__ csrEn, int* __restrict__ csrNe, int* __restrict__ csrNs,
    unsigned* __restrict__ x4b, unsigned* __restrict__ xwb,
    float* __restrict__ rowv, float* __restrict__ csx4, float* __restrict__ csxw)
{
    __shared__ float srow[16];
    __shared__ float sxv[256];
    const int t = threadIdx.x;

    if (blockIdx.x == 512) {
        // ---- analytic colsums: csx4 = sx@W2T(bf16), csxw = sx@WWT + Nn*bW3
        float s = 0.f;
        for (int b2 = 0; b2 < 128; ++b2) s += sxPart[b2 * 256 + t];
        sxv[t] = s;
        __syncthreads();
        const int c  = t & 127;
        const int g  = c >> 5, r = c & 31;
        const int pos = 2 * (g * 16 + (r & 15)) + (r >> 4);   // slot layout
        if (t < 128) {
            float acc = 0.f;
            for (int k = 0; k < 256; ++k)
                acc = fmaf(sxv[k], bf2f(W2T[(size_t)c * DIN + k]), acc);
            csx4[pos] = acc;
        } else {
            float acc = 0.f;
            for (int k = 0; k < 256; ++k)
                acc = fmaf(sxv[k], bf2f(WWT[(size_t)c * DIN + k]), acc);
            csxw[pos] = acc + (float)Nn * bW3[c];
        }
        return;
    }

    const int lane = t & 63;
    const int wv   = t >> 6;
    const int n16  = lane & 15;
    const int quad = lane >> 4;
    const int r0   = blockIdx.x * 16;
    const int n0   = wv * 32;

    // ---- CSR build ----
    const unsigned gid = blockIdx.x * 256 + t;
    if (gid < NNZ) {
        const int n = hidx[gid];
        const int e = hidx[NNZ + gid];
        const unsigned word = (unsigned)n * (unsigned)Ee + (unsigned)e;
        const unsigned bit  = 1u << (word & 31u);
        const unsigned old  = atomicOr(&bitmap[word >> 5], bit);
        if (!(old & bit)) {
            const int pe = atomicAdd(&degE[e], 1);
            if (pe < EC) {
                csrEn[e * EC + pe] = n;
                const int pn = atomicAdd(&degN[n], 1);
                if (pn < NC) {
                    csrNe[n * NC + pn] = e;
                    csrNs[n * NC + pn] = e * EC + pe;
                }
            }
        }
    }

    // ---- MFMA main loop ----
    f32x4 acc4[2], accw[2];
#pragma unroll
    for (int nt = 0; nt < 2; ++nt) {
        acc4[nt] = (f32x4){0.f, 0.f, 0.f, 0.f};
        accw[nt] = (f32x4){0.f, 0.f, 0.f, 0.f};
    }
#pragma unroll
    for (int k0 = 0; k0 < DIN; k0 += 32) {
        const int kb = k0 + quad * 8;
        const float4 xa = *(const float4*)&x[(size_t)(r0 + n16) * DIN + kb];
        const float4 xb = *(const float4*)&x[(size_t)(r0 + n16) * DIN + kb + 4];
        short8 af;
        af[0] = f2bf(xa.x); af[1] = f2bf(xa.y); af[2] = f2bf(xa.z); af[3] = f2bf(xa.w);
        af[4] = f2bf(xb.x); af[5] = f2bf(xb.y); af[6] = f2bf(xb.z); af[7] = f2bf(xb.w);
#pragma unroll
        for (int nt = 0; nt < 2; ++nt) {
            const int col = n0 + nt * 16 + n16;
            const short8 b4 = *(const short8*)&W2T[(size_t)col * DIN + kb];
            const short8 bw = *(const short8*)&WWT[(size_t)col * DIN + kb];
            acc4[nt] = __builtin_amdgcn_mfma_f32_16x16x32_bf16(af, b4, acc4[nt], 0, 0, 0);
            accw[nt] = __builtin_amdgcn_mfma_f32_16x16x32_bf16(af, bw, accw[nt], 0, 0, 0);
        }
    }

    // ---- writeback (slot layout, paired dword stores) + rowv epilogue ----
    float bwv[2], qv[2];
#pragma unroll
    for (int nt = 0; nt < 2; ++nt) {
        const int col = n0 + nt * 16 + n16;
        bwv[nt] = bW3[col];
        qv[nt]  = q[col];
    }
    const int s = wv * 16 + n16;   // pair-slot: cols (n0+n16, n0+16+n16)
#pragma unroll
    for (int reg = 0; reg < 4; ++reg) {
        const int row = r0 + quad * 4 + reg;
        x4b[(size_t)row * 64 + s] = packbf2(acc4[0][reg], acc4[1][reg]);
        xwb[(size_t)row * 64 + s] = packbf2(accw[0][reg] + bwv[0],
                                            accw[1][reg] + bwv[1]);
    }
    float pr[4];
#pragma unroll
    for (int reg = 0; reg < 4; ++reg)
        pr[reg] = qv[0] * acc4[0][reg] + qv[1] * acc4[1][reg];
#pragma unroll
    for (int m = 8; m; m >>= 1) {
#pragma unroll
        for (int reg = 0; reg < 4; ++reg) pr[reg] += __shfl_xor(pr[reg], m, 64);
    }
    if (t < 16) srow[t] = 0.f;
    __syncthreads();
    if (n16 == 0) {
#pragma unroll
        for (int reg = 0; reg < 4; ++reg) atomicAdd(&srow[quad * 4 + reg], pr[reg]);
    }
    __syncthreads();
    if (t < 16) rowv[r0 + t] = srow[t] * TEMPR;
}

// ---------------------------------------------------------------------------
// K2: per-edge softmax1 -> Sval + ws scatter; bf16 gathers e4b / G1b.
//     (round-9 structure: pure edge blocks, no redux tail)
// ---------------------------------------------------------------------------
__global__ __launch_bounds__(128, 4) void k_edge1(
    const int* __restrict__ degE, const int* __restrict__ csrEn,
    const float* __restrict__ rowv,
    const float* __restrict__ csx4, const float* __restrict__ csxw,
    const unsigned* __restrict__ x4b, const unsigned* __restrict__ xwb,
    float* __restrict__ Sval, unsigned* __restrict__ e4b, unsigned* __restrict__ G1b,
    float* __restrict__ wsArr)
{
    __shared__ int   sN[2][EC];
    __shared__ float sS[2][EC];
    const int t    = threadIdx.x;
    const int w    = t >> 6;
    const int lane = t & 63;
    const int e    = blockIdx.x * 2 + w;
    const int deg  = min(degE[e], EC);
    const float ue = deg ? 1.0f / ((float)Nn + (float)deg * EM1) : 2.0f / (float)Nn;

    int   n0 = 0, n1 = 0;
    float r0 = -INFINITY, r1 = -INFINITY;
    if (lane < deg)      { n0 = csrEn[e * EC + lane];      r0 = rowv[n0]; }
    if (lane + 64 < deg) { n1 = csrEn[e * EC + lane + 64]; r1 = rowv[n1]; }
    const float m  = wave_max64(fmaxf(r0, r1));
    const float e0 = (lane < deg)      ? expf(r0 - m) : 0.f;
    const float e1 = (lane + 64 < deg) ? expf(r1 - m) : 0.f;
    const float Z  = wave_sum64(e0 + e1);
    const float inv = deg ? 1.0f / Z : 0.f;
    const float base = EM1 * ue;
    if (lane < deg) {
        const float sv = fmaf(e0, inv, base);
        sN[w][lane] = n0; sS[w][lane] = sv;
        Sval[e * EC + lane] = sv;
        atomicAdd(&wsArr[n0], ue * sv);
    }
    if (lane + 64 < deg) {
        const float sv = fmaf(e1, inv, base);
        sN[w][lane + 64] = n1; sS[w][lane + 64] = sv;
        Sval[e * EC + lane + 64] = sv;
        atomicAdd(&wsArr[n1], ue * sv);
    }

    const float2 cw = *(const float2*)&csxw[lane * 2];
    const float2 c4 = *(const float2*)&csx4[lane * 2];
    float2 aE = make_float2(ue * cw.x, ue * cw.y);
    float2 aG = make_float2(ue * c4.x, ue * c4.y);
    int j = 0;
    for (; j + 16 <= deg; j += 16) {
        int ai[16]; float bi[16]; unsigned tu[16], fu[16];
#pragma unroll
        for (int k = 0; k < 16; ++k) { ai[k] = sN[w][j+k]; bi[k] = sS[w][j+k]; }
#pragma unroll
        for (int k = 0; k < 16; ++k) {
            tu[k] = xwb[(size_t)ai[k] * 64 + lane];
            fu[k] = x4b[(size_t)ai[k] * 64 + lane];
        }
#pragma unroll
        for (int k = 0; k < 16; ++k) {
            const float2 tv = unpackbf2(tu[k]);
            const float2 fv = unpackbf2(fu[k]);
            aE.x = fmaf(bi[k], tv.x, aE.x); aE.y = fmaf(bi[k], tv.y, aE.y);
            aG.x = fmaf(bi[k], fv.x, aG.x); aG.y = fmaf(bi[k], fv.y, aG.y);
        }
    }
    for (; j + 8 <= deg; j += 8) {
        int ai[8]; float bi[8]; unsigned tu[8], fu[8];
#pragma unroll
        for (int k = 0; k < 8; ++k) { ai[k] = sN[w][j+k]; bi[k] = sS[w][j+k]; }
#pragma unroll
        for (int k = 0; k < 8; ++k) {
            tu[k] = xwb[(size_t)ai[k] * 64 + lane];
            fu[k] = x4b[(size_t)ai[k] * 64 + lane];
        }
#pragma unroll
        for (int k = 0; k < 8; ++k) {
            const float2 tv = unpackbf2(tu[k]);
            const float2 fv = unpackbf2(fu[k]);
            aE.x = fmaf(bi[k], tv.x, aE.x); aE.y = fmaf(bi[k], tv.y, aE.y);
            aG.x = fmaf(bi[k], fv.x, aG.x); aG.y = fmaf(bi[k], fv.y, aG.y);
        }
    }
    for (; j < deg; ++j) {
        const int   a = sN[w][j];
        const float b = sS[w][j];
        const float2 tv = unpackbf2(xwb[(size_t)a * 64 + lane]);
        const float2 fv = unpackbf2(x4b[(size_t)a * 64 + lane]);
        aE.x = fmaf(b, tv.x, aE.x); aE.y = fmaf(b, tv.y, aE.y);
        aG.x = fmaf(b, fv.x, aG.x); aG.y = fmaf(b, fv.y, aG.y);
    }
    e4b[(size_t)e * 64 + lane] = packbf2(aE.x, aE.y);
    G1b[(size_t)e * 64 + lane] = packbf2(aG.x, aG.y);
}

// ---------------------------------------------------------------------------
// K3: merged (round-9 structure). Blocks 0..63: weighted colsums
//     (vn/tw/ws on x4b) -> vxg/twg/wsg + c2g. Blocks 64..: per-node
//     softmax2 (one node/wave, 8 edge-slots x 8 dim-lanes) -> Tval.
// ---------------------------------------------------------------------------
__global__ __launch_bounds__(256) void k_nodeB(
    const int* __restrict__ degN, const int* __restrict__ degE,
    const int* __restrict__ csrNe,
    const int* __restrict__ csrNs, const unsigned* __restrict__ x4b,
    const unsigned* __restrict__ e4b, const float* __restrict__ wsArr,
    float* __restrict__ Tval,
    float* __restrict__ vxg, float* __restrict__ twg, float* __restrict__ wsg,
    float* __restrict__ c2g)
{
    const int t    = threadIdx.x;
    const int w    = t >> 6;
    const int lane = t & 63;
    const int b    = blockIdx.x;

    if (b < 64) {                         // ---- redux part ----
        float2 av = {0.f, 0.f}, at2 = {0.f, 0.f}, aw = {0.f, 0.f};
        for (int k = 0; k < 32; ++k) {
            const int n   = b * 128 + w + k * 4;
            const int deg = min(degN[n], NC);
            const float vn = deg ? 1.0f / ((float)Ee + (float)deg * EM1)
                                 : 2.0f / (float)Ee;
            const float tw = deg ? fmaf((float)deg * EM1, vn, 1.0f) : 0.f;
            const float wsn = wsArr[n];
            const float2 xv = unpackbf2(x4b[(size_t)n * 64 + lane]);
            av.x  = fmaf(vn,  xv.x, av.x);  av.y  = fmaf(vn,  xv.y, av.y);
            at2.x = fmaf(tw,  xv.x, at2.x); at2.y = fmaf(tw,  xv.y, at2.y);
            aw.x  = fmaf(wsn, xv.x, aw.x);  aw.y  = fmaf(wsn, xv.y, aw.y);
        }
        atomicAdd(&vxg[lane*2+0], av.x);  atomicAdd(&vxg[lane*2+1], av.y);
        atomicAdd(&twg[lane*2+0], at2.x); atomicAdd(&twg[lane*2+1], at2.y);
        atomicAdd(&wsg[lane*2+0], aw.x);  atomicAdd(&wsg[lane*2+1], aw.y);
        // ---- c2g (edges 0..4095 in blocks 0..15) ----
        const int gid = b * 256 + t;
        if (gid < Ee) {
            const int de = min(degE[gid], EC);
            const float ue = de ? 1.0f / ((float)Nn + (float)de * EM1)
                                : 2.0f / (float)Nn;
            const float v = wave_sum64(ue * ue);
            if (lane == 0) atomicAdd(c2g, v);
        }
        return;
    }

    // ---- node2 part ----
    const int es   = lane >> 3;           // edge slot within pass (0..7)
    const int dl   = lane & 7;            // dim-lane
    const int n    = (b - 64) * 4 + w;    // one node per wave
    const int deg  = min(degN[n], NC);
    if (!deg) return;                     // wave-uniform
    const float vn = 1.0f / ((float)Ee + (float)deg * EM1);

    const uint4* xr = (const uint4*)&x4b[(size_t)n * 64];
    const uint4 xua = xr[dl * 2], xub = xr[dl * 2 + 1];
    const float2 x0 = unpackbf2(xua.x), x1 = unpackbf2(xua.y),
                 x2 = unpackbf2(xua.z), x3 = unpackbf2(xua.w),
                 x4v = unpackbf2(xub.x), x5 = unpackbf2(xub.y),
                 x6 = unpackbf2(xub.z), x7 = unpackbf2(xub.w);

    float dps[6]; float exs[6]; int slots[6];
    float m = -INFINITY;
#pragma unroll
    for (int p = 0; p < 6; ++p) {
        dps[p] = -INFINITY; slots[p] = 0;
        if (p * 8 >= deg) continue;       // wave-uniform branch
        const int j = p * 8 + es;
        int ej = 0;
        if (j < deg) { ej = csrNe[n * NC + j]; slots[p] = csrNs[n * NC + j]; }
        const uint4* er = (const uint4*)&e4b[(size_t)ej * 64];
        const uint4 ea = er[dl * 2], eb = er[dl * 2 + 1];
        float d0 = 0.f, d1 = 0.f, d2 = 0.f, d3 = 0.f;
        { const float2 ev = unpackbf2(ea.x); d0 = fmaf(ev.x, x0.x, d0); d0 = fmaf(ev.y, x0.y, d0); }
        { const float2 ev = unpackbf2(ea.y); d1 = fmaf(ev.x, x1.x, d1); d1 = fmaf(ev.y, x1.y, d1); }
        { const float2 ev = unpackbf2(ea.z); d2 = fmaf(ev.x, x2.x, d2); d2 = fmaf(ev.y, x2.y, d2); }
        { const float2 ev = unpackbf2(ea.w); d3 = fmaf(ev.x, x3.x, d3); d3 = fmaf(ev.y, x3.y, d3); }
        { const float2 ev = unpackbf2(eb.x); d0 = fmaf(ev.x, x4v.x, d0); d0 = fmaf(ev.y, x4v.y, d0); }
        { const float2 ev = unpackbf2(eb.y); d1 = fmaf(ev.x, x5.x, d1); d1 = fmaf(ev.y, x5.y, d1); }
        { const float2 ev = unpackbf2(eb.z); d2 = fmaf(ev.x, x6.x, d2); d2 = fmaf(ev.y, x6.y, d2); }
        { const float2 ev = unpackbf2(eb.w); d3 = fmaf(ev.x, x7.x, d3); d3 = fmaf(ev.y, x7.y, d3); }
        float dot = (d0 + d1) + (d2 + d3);
        dot += __shfl_xor(dot, 1, 64);
        dot += __shfl_xor(dot, 2, 64);
        dot += __shfl_xor(dot, 4, 64);
        dot = (j < deg) ? dot * TEMPR : -INFINITY;
        dps[p] = dot;
        float mm = fmaxf(dot, __shfl_xor(dot, 8, 64));
        mm = fmaxf(mm, __shfl_xor(mm, 16, 64));
        mm = fmaxf(mm, __shfl_xor(mm, 32, 64));
        m = fmaxf(m, mm);
    }
    float Z = 0.f;
#pragma unroll
    for (int p = 0; p < 6; ++p) {
        exs[p] = 0.f;
        if (p * 8 >= deg) continue;
        const float ex = (p * 8 + es < deg) ? expf(dps[p] - m) : 0.f;
        exs[p] = ex;
        float sum = ex + __shfl_xor(ex, 8, 64);
        sum += __shfl_xor(sum, 16, 64);
        sum += __shfl_xor(sum, 32, 64);
        Z += sum;
    }
    const float invZ = 1.0f / Z;
#pragma unroll
    for (int p = 0; p < 6; ++p) {
        if (p * 8 >= deg) continue;
        if (dl == 0 && p * 8 + es < deg)
            Tval[slots[p]] = fmaf(EM1, vn, exs[p] * invZ);
    }
}

// ---------------------------------------------------------------------------
// K4: per-edge: G2b[e] = vx + sum_{n in e} T[e,n] * x4[n].
// ---------------------------------------------------------------------------
__global__ __launch_bounds__(128, 4) void k_g2(
    const int* __restrict__ degE, const int* __restrict__ csrEn,
    const float* __restrict__ Tval, const float* __restrict__ vxg,
    const unsigned* __restrict__ x4b, unsigned* __restrict__ G2b)
{
    const int t    = threadIdx.x;
    const int w    = t >> 6;
    const int lane = t & 63;
    const int e    = blockIdx.x * 2 + w;
    const int deg  = min(degE[e], EC);
    float2 acc = *(const float2*)&vxg[lane * 2];
    int j = 0;
    for (; j + 16 <= deg; j += 16) {
        int ai[16]; float bi[16]; unsigned fu[16];
#pragma unroll
        for (int k = 0; k < 16; ++k) { ai[k] = csrEn[e*EC+j+k]; bi[k] = Tval[e*EC+j+k]; }
#pragma unroll
        for (int k = 0; k < 16; ++k)
            fu[k] = x4b[(size_t)ai[k] * 64 + lane];
#pragma unroll
        for (int k = 0; k < 16; ++k) {
            const float2 fv = unpackbf2(fu[k]);
            acc.x = fmaf(bi[k], fv.x, acc.x); acc.y = fmaf(bi[k], fv.y, acc.y);
        }
    }
    for (; j + 8 <= deg; j += 8) {
        int ai[8]; float bi[8]; unsigned fu[8];
#pragma unroll
        for (int k = 0; k < 8; ++k) { ai[k] = csrEn[e*EC+j+k]; bi[k] = Tval[e*EC+j+k]; }
#pragma unroll
        for (int k = 0; k < 8; ++k)
            fu[k] = x4b[(size_t)ai[k] * 64 + lane];
#pragma unroll
        for (int k = 0; k < 8; ++k) {
            const float2 fv = unpackbf2(fu[k]);
            acc.x = fmaf(bi[k], fv.x, acc.x); acc.y = fmaf(bi[k], fv.y, acc.y);
        }
    }
    for (; j < deg; ++j) {
        const int   a = csrEn[e*EC+j];
        const float b = Tval[e*EC+j];
        const float2 fv = unpackbf2(x4b[(size_t)a * 64 + lane]);
        acc.x = fmaf(b, fv.x, acc.x); acc.y = fmaf(b, fv.y, acc.y);
    }
    G2b[(size_t)e * 64 + lane] = packbf2(acc.x, acc.y);
}

// ---------------------------------------------------------------------------
// K5: final per-node combine + elu.  Unscrambles slot layout.
// ---------------------------------------------------------------------------
__global__ __launch_bounds__(128, 4) void k_final(
    const int* __restrict__ degN, const int* __restrict__ csrNe,
    const int* __restrict__ csrNs, const float* __restrict__ Sval,
    const float* __restrict__ Tval,
    const float* __restrict__ c2g, const float* __restrict__ csx4,
    const float* __restrict__ wsg, const float* __restrict__ vxg,
    const float* __restrict__ twg,
    const unsigned* __restrict__ G1b, const unsigned* __restrict__ G2b,
    float* __restrict__ out)
{
    const int t    = threadIdx.x;
    const int w    = t >> 6;
    const int lane = t & 63;
    const int n    = blockIdx.x * 2 + w;
    const int deg  = min(degN[n], NC);
    const float vn = deg ? 1.0f / ((float)Ee + (float)deg * EM1) : 2.0f / (float)Ee;
    const float c2 = *c2g;
    const float2 c4v = *(const float2*)&csx4[lane * 2];
    const float2 wsv = *(const float2*)&wsg[lane * 2];
    const float2 vxv = *(const float2*)&vxg[lane * 2];
    const float2 twv = *(const float2*)&twg[lane * 2];
    float2 acc;
    acc.x = fmaf(c2, c4v.x, wsv.x) + vn * fmaf((float)Ee, vxv.x, twv.x);
    acc.y = fmaf(c2, c4v.y, wsv.y) + vn * fmaf((float)Ee, vxv.y, twv.y);
    int j = 0;
    for (; j + 8 <= deg; j += 8) {
        int ei[8], si[8]; float sv[8], tv[8]; unsigned g1u[8], g2u[8];
#pragma unroll
        for (int k = 0; k < 8; ++k) {
            ei[k] = csrNe[n*NC+j+k]; si[k] = csrNs[n*NC+j+k];
        }
#pragma unroll
        for (int k = 0; k < 8; ++k) {
            sv[k] = Sval[si[k]]; tv[k] = Tval[si[k]];
            g1u[k] = G1b[(size_t)ei[k] * 64 + lane];
            g2u[k] = G2b[(size_t)ei[k] * 64 + lane];
        }
#pragma unroll
        for (int k = 0; k < 8; ++k) {
            const float2 g1 = unpackbf2(g1u[k]);
            const float2 g2 = unpackbf2(g2u[k]);
            acc.x = fmaf(sv[k], g1.x, acc.x); acc.y = fmaf(sv[k], g1.y, acc.y);
            acc.x = fmaf(tv[k], g2.x, acc.x); acc.y = fmaf(tv[k], g2.y, acc.y);
        }
    }
    for (; j + 4 <= deg; j += 4) {
        int ei[4], si[4]; float sv[4], tv[4]; unsigned g1u[4], g2u[4];
#pragma unroll
        for (int k = 0; k < 4; ++k) {
            ei[k] = csrNe[n*NC+j+k]; si[k] = csrNs[n*NC+j+k];
        }
#pragma unroll
        for (int k = 0; k < 4; ++k) {
            sv[k] = Sval[si[k]]; tv[k] = Tval[si[k]];
            g1u[k] = G1b[(size_t)ei[k] * 64 + lane];
            g2u[k] = G2b[(size_t)ei[k] * 64 + lane];
        }
#pragma unroll
        for (int k = 0; k < 4; ++k) {
            const float2 g1 = unpackbf2(g1u[k]);
            const float2 g2 = unpackbf2(g2u[k]);
            acc.x = fmaf(sv[k], g1.x, acc.x); acc.y = fmaf(sv[k], g1.y, acc.y);
            acc.x = fmaf(tv[k], g2.x, acc.x); acc.y = fmaf(tv[k], g2.y, acc.y);
        }
    }
    for (; j < deg; ++j) {
        const int ea = csrNe[n*NC+j];
        const int sa = csrNs[n*NC+j];
        const float sva = Sval[sa], tva = Tval[sa];
        const float2 g1a = unpackbf2(G1b[(size_t)ea * 64 + lane]);
        const float2 g2a = unpackbf2(G2b[(size_t)ea * 64 + lane]);
        acc.x = fmaf(sva, g1a.x, acc.x); acc.y = fmaf(sva, g1a.y, acc.y);
        acc.x = fmaf(tva, g2a.x, acc.x); acc.y = fmaf(tva, g2a.y, acc.y);
    }
    acc.x = acc.x > 0.f ? acc.x : expm1f(acc.x);
    acc.y = acc.y > 0.f ? acc.y : expm1f(acc.y);
    // unscramble slot layout: slot holds dims lo and lo+16
    const int lo = ((lane >> 4) << 5) + (lane & 15);
    out[(size_t)n * DOUT + lo]      = acc.x;
    out[(size_t)n * DOUT + lo + 16] = acc.y;
}

// ---------------------------------------------------------------------------
extern "C" void kernel_launch(void* const* d_in, const int* in_sizes, int n_in,
                              void* d_out, int out_size, void* d_ws, size_t ws_size,
                              hipStream_t stream)
{
    const float* x    = (const float*)d_in[0];
    const float* W    = (const float*)d_in[1];
    const float* W2   = (const float*)d_in[2];
    const float* W3   = (const float*)d_in[3];
    const float* bias = (const float*)d_in[4];
    const float* q    = (const float*)d_in[5];
    const int*   hidx = (const int*)d_in[6];
    float* out = (float*)d_out;

    char* wsp = (char*)d_ws;
    size_t o = 0;
    auto take = [&](size_t bytes) {
        size_t r = o; o += (bytes + 255) & ~(size_t)255; return r;
    };
    // --- zero-initialized region (zeroed by k_ww3 blocks 41..168) ---
    unsigned* bitmap = (unsigned*)(wsp + take((size_t)Nn * Ee / 8));   // 4 MB
    int*   degE  = (int*)  (wsp + take((size_t)Ee * 4));
    int*   degN  = (int*)  (wsp + take((size_t)Nn * 4));
    float* wsArr = (float*)(wsp + take((size_t)Nn * 4));
    float* c2g   = (float*)(wsp + take(4));
    float* vxg   = (float*)(wsp + take(DOUT * 4));
    float* twg   = (float*)(wsp + take(DOUT * 4));
    float* wsg   = (float*)(wsp + take(DOUT * 4));
    const size_t zbytes = o;
    // --- fully-overwritten scratch ---
    float*    csx4  = (float*)   (wsp + take(DOUT * 4));
    float*    csxw  = (float*)   (wsp + take(DOUT * 4));
    float*    sxPart= (float*)   (wsp + take(128 * 256 * 4));         // 128 KB
    unsigned* x4b   = (unsigned*)(wsp + take((size_t)Nn * 64 * 4));   // bf16 pairs
    unsigned* xwb   = (unsigned*)(wsp + take((size_t)Nn * 64 * 4));   // bf16 pairs
    float*    rowv  = (float*)   (wsp + take((size_t)Nn * 4));
    int*      csrEn = (int*)     (wsp + take((size_t)Ee * EC * 4));
    float*    Sval  = (float*)   (wsp + take((size_t)Ee * EC * 4));
    float*    Tval  = (float*)   (wsp + take((size_t)Ee * EC * 4));
    int*      csrNe = (int*)     (wsp + take((size_t)Nn * NC * 4));
    int*      csrNs = (int*)     (wsp + take((size_t)Nn * NC * 4));
    unsigned* e4b   = (unsigned*)(wsp + take((size_t)Ee * 64 * 4));   // bf16 pairs
    unsigned* G1b   = (unsigned*)(wsp + take((size_t)Ee * 64 * 4));   // bf16 pairs
    unsigned* G2b   = (unsigned*)(wsp + take((size_t)Ee * 64 * 4));   // bf16 pairs
    short*    W2T   = (short*)   (wsp + take((size_t)DOUT * DIN * 2));
    short*    WWT   = (short*)   (wsp + take((size_t)DOUT * DIN * 2));
    float*    bW3   = (float*)   (wsp + take(DOUT * 4));
    (void)ws_size; (void)in_sizes; (void)n_in; (void)out_size;

    k_ww3   <<<169,          256, 0, stream>>>(x, W, W2, W3, bias, W2T, WWT, bW3,
                                               sxPart, (uint4*)d_ws,
                                               (unsigned)(zbytes / 16));
    k_gemm1f<<<513,          256, 0, stream>>>(x, W2T, WWT, bW3, q, hidx, sxPart,
                                               bitmap, degE, degN, csrEn, csrNe,
                                               csrNs, x4b, xwb, rowv, csx4, csxw);
    k_edge1 <<<Ee / 2,       128, 0, stream>>>(degE, csrEn, rowv, csx4, csxw,
                                               x4b, xwb, Sval, e4b, G1b, wsArr);
    k_nodeB <<<64 + Nn / 4,  256, 0, stream>>>(degN, degE, csrNe, csrNs, x4b, e4b,
                                               wsArr, Tval, vxg, twg, wsg, c2g);
    k_g2    <<<Ee / 2,       128, 0, stream>>>(degE, csrEn, Tval, vxg, x4b, G2b);
    k_final <<<Nn / 2,       128, 0, stream>>>(degN, csrNe, csrNs, Sval, Tval,
                                               c2g, csx4, wsg, vxg, twg, G1b, G2b,
                                               out);
}

// Round 12
// 154.013 us; speedup vs baseline: 1.0738x; 1.0099x over previous
//
#include <hip/hip_runtime.h>
#include <math.h>

// Problem constants (match reference)
constexpr int Nn   = 8192;
constexpr int Ee   = 4096;
constexpr int DIN  = 256;
constexpr int DOUT = 128;
constexpr int NNZ  = 65536;
constexpr int EC   = 96;   // capacity: nodes per edge (deg ~ Poisson(16))
constexpr int NC   = 48;   // capacity: edges per node (deg ~ Poisson(8))

#define TEMPR 0.08838834764831845f   // 1/sqrt(128)
#define EM1   1.7182818284590452f    // e - 1

// Pair-slot layout: slot s in [0,64) holds dims L(s)=(s>>4)*32+(s&15) and
// H(s)=L(s)+16. All per-dim bf16 rows and fp32 vectors use this layout;
// only k_final's output store unscrambles.
//
// Round-12 theme: hoist x fp32->bf16 conversion out of the GEMM inner loop.
// ww3's 128 colsum blocks already stream all of x; they now also emit a bf16
// copy xb (same f2bf rounding -> bit-identical A fragments). gemm1f's K-loop
// loads one short8 from xb instead of 2 float4 + 16 f2bf VALU ops.

typedef __attribute__((ext_vector_type(8))) short short8;
typedef __attribute__((ext_vector_type(4))) float f32x4;

static __device__ __forceinline__ float wave_sum64(float v) {
#pragma unroll
    for (int m = 32; m; m >>= 1) v += __shfl_xor(v, m, 64);
    return v;
}
static __device__ __forceinline__ float wave_max64(float v) {
#pragma unroll
    for (int m = 32; m; m >>= 1) v = fmaxf(v, __shfl_xor(v, m, 64));
    return v;
}
static __device__ __forceinline__ short f2bf(float f) {
    union { float f; unsigned u; } v; v.f = f;
    const unsigned r = (v.u + 0x7FFFu + ((v.u >> 16) & 1u)) >> 16;
    return (short)r;
}
static __device__ __forceinline__ unsigned packbf2(float a, float b) {
    return ((unsigned)(unsigned short)f2bf(a)) |
           (((unsigned)(unsigned short)f2bf(b)) << 16);
}
static __device__ __forceinline__ float2 unpackbf2(unsigned u) {
    union { unsigned u; float f; } lo, hi;
    lo.u = u << 16; hi.u = u & 0xFFFF0000u;
    return make_float2(lo.f, hi.f);
}
static __device__ __forceinline__ float bf2f(short s) {
    union { unsigned u; float f; } v;
    v.u = ((unsigned)(unsigned short)s) << 16;
    return v.f;
}

// ---------------------------------------------------------------------------
// K0: prologue. blocks 0..31: WWT; 32..39: W2T; 40: bW3;
//     41..168: zero z-region + x-colsum partials + bf16 copy xb (64 rows ea).
// ---------------------------------------------------------------------------
__global__ __launch_bounds__(256) void k_ww3(
    const float* __restrict__ x,
    const float* __restrict__ W, const float* __restrict__ W2,
    const float* __restrict__ W3, const float* __restrict__ bias,
    short* __restrict__ W2T, short* __restrict__ WWT, float* __restrict__ bW3,
    float* __restrict__ sxPart, uint2* __restrict__ xb2,
    uint4* __restrict__ zb, unsigned zTot16)
{
    __shared__ float sW[8][128];
    __shared__ float sxl[256];
    const int b = blockIdx.x;
    const int t = threadIdx.x;
    if (b < 32) {
        const int r0 = b * 8;
        for (int i = t; i < 1024; i += 256)
            sW[i >> 7][i & 127] = W[(size_t)(r0 + (i >> 7)) * DOUT + (i & 127)];
        __syncthreads();
        const int c  = t & 127;
        const int rh = (t >> 7) * 4;
        float acc[4] = {0.f, 0.f, 0.f, 0.f};
        for (int k = 0; k < 128; ++k) {
            const float w3 = W3[(size_t)k * DOUT + c];
#pragma unroll
            for (int i = 0; i < 4; ++i) acc[i] = fmaf(sW[rh + i][k], w3, acc[i]);
        }
#pragma unroll
        for (int i = 0; i < 4; ++i)
            WWT[(size_t)c * DIN + (r0 + rh + i)] = f2bf(acc[i]);
    } else if (b < 40) {
        const int k0 = (b - 32) * 32;
        for (int i = t; i < 32 * 128; i += 256) {
            const int k = k0 + (i >> 7);
            const int n = i & 127;
            W2T[(size_t)n * DIN + k] = f2bf(W2[(size_t)k * DOUT + n]);
        }
    } else if (b == 40) {
        if (t < 128) {
            float acc = 0.f;
            for (int k = 0; k < 128; ++k)
                acc = fmaf(bias[k], W3[(size_t)k * DOUT + t], acc);
            bW3[t] = acc;
        }
    } else {
        const int zb0 = b - 41;             // 0..127
        uint4 z; z.x = z.y = z.z = z.w = 0u;
        for (unsigned i = (unsigned)zb0 * 256u + t; i < zTot16;
             i += 128u * 256u)
            zb[i] = z;
        // ---- x colsum partial + bf16 copy: rows [zb0*64, zb0*64+64) ----
        const int lane = t & 63;
        const int wv   = t >> 6;
        float a0 = 0.f, a1 = 0.f, a2 = 0.f, a3 = 0.f;
#pragma unroll 8
        for (int r = 0; r < 16; ++r) {
            const int row = zb0 * 64 + wv * 16 + r;
            const float4 v = *(const float4*)&x[(size_t)row * DIN + lane * 4];
            a0 += v.x; a1 += v.y; a2 += v.z; a3 += v.w;
            // bf16 copy: k = lane*4..lane*4+3 -> uint2 at [row*64 + lane]
            xb2[(size_t)row * 64 + lane] =
                make_uint2(packbf2(v.x, v.y), packbf2(v.z, v.w));
        }
        sxl[t] = 0.f;
        __syncthreads();
        atomicAdd(&sxl[lane * 4 + 0], a0);
        atomicAdd(&sxl[lane * 4 + 1], a1);
        atomicAdd(&sxl[lane * 4 + 2], a2);
        atomicAdd(&sxl[lane * 4 + 3], a3);
        __syncthreads();
        sxPart[zb0 * 256 + t] = sxl[t];
    }
}

// ---------------------------------------------------------------------------
// K1: blocks 0..511: MFMA GEMM (A from bf16 xb, no conversions) + CSR build
//     + rowv. block 512: reduce sxPart -> sx; matvecs -> csx4/csxw.
// ---------------------------------------------------------------------------
__global__ __launch_bounds__(256) void k_gemm1f(
    const short* __restrict__ xb, const short* __restrict__ W2T,
    const short* __restrict__ WWT, const float* __restrict__ bW3,
    const float* __restrict__ q, const int* __restrict__ hidx,
    const float* __restrict__ sxPart,
    unsigned* __restrict__ bitmap, int* __restrict__ degE, int* __restrict__ degN,
    int* __restrict__ csrEn, int* __restrict__ csrNe, int* __restrict__ csrNs,
    unsigned* __restrict__ x4b, unsigned* __restrict__ xwb,
    float* __restrict__ rowv, float* __restrict__ csx4, float* __restrict__ csxw)
{
    __shared__ float srow[16];
    __shared__ float sxv[256];
    const int t = threadIdx.x;

    if (blockIdx.x == 512) {
        // ---- analytic colsums: csx4 = sx@W2T(bf16), csxw = sx@WWT + Nn*bW3
        float s = 0.f;
        for (int b2 = 0; b2 < 128; ++b2) s += sxPart[b2 * 256 + t];
        sxv[t] = s;
        __syncthreads();
        const int c  = t & 127;
        const int g  = c >> 5, r = c & 31;
        const int pos = 2 * (g * 16 + (r & 15)) + (r >> 4);   // slot layout
        if (t < 128) {
            float acc = 0.f;
            for (int k = 0; k < 256; ++k)
                acc = fmaf(sxv[k], bf2f(W2T[(size_t)c * DIN + k]), acc);
            csx4[pos] = acc;
        } else {
            float acc = 0.f;
            for (int k = 0; k < 256; ++k)
                acc = fmaf(sxv[k], bf2f(WWT[(size_t)c * DIN + k]), acc);
            csxw[pos] = acc + (float)Nn * bW3[c];
        }
        return;
    }

    const int lane = t & 63;
    const int wv   = t >> 6;
    const int n16  = lane & 15;
    const int quad = lane >> 4;
    const int r0   = blockIdx.x * 16;
    const int n0   = wv * 32;

    // ---- CSR build ----
    const unsigned gid = blockIdx.x * 256 + t;
    if (gid < NNZ) {
        const int n = hidx[gid];
        const int e = hidx[NNZ + gid];
        const unsigned word = (unsigned)n * (unsigned)Ee + (unsigned)e;
        const unsigned bit  = 1u << (word & 31u);
        const unsigned old  = atomicOr(&bitmap[word >> 5], bit);
        if (!(old & bit)) {
            const int pe = atomicAdd(&degE[e], 1);
            if (pe < EC) {
                csrEn[e * EC + pe] = n;
                const int pn = atomicAdd(&degN[n], 1);
                if (pn < NC) {
                    csrNe[n * NC + pn] = e;
                    csrNs[n * NC + pn] = e * EC + pe;
                }
            }
        }
    }

    // ---- MFMA main loop (A fragments direct from bf16 xb) ----
    f32x4 acc4[2], accw[2];
#pragma unroll
    for (int nt = 0; nt < 2; ++nt) {
        acc4[nt] = (f32x4){0.f, 0.f, 0.f, 0.f};
        accw[nt] = (f32x4){0.f, 0.f, 0.f, 0.f};
    }
#pragma unroll
    for (int k0 = 0; k0 < DIN; k0 += 32) {
        const int kb = k0 + quad * 8;
        const short8 af = *(const short8*)&xb[(size_t)(r0 + n16) * DIN + kb];
#pragma unroll
        for (int nt = 0; nt < 2; ++nt) {
            const int col = n0 + nt * 16 + n16;
            const short8 b4 = *(const short8*)&W2T[(size_t)col * DIN + kb];
            const short8 bw = *(const short8*)&WWT[(size_t)col * DIN + kb];
            acc4[nt] = __builtin_amdgcn_mfma_f32_16x16x32_bf16(af, b4, acc4[nt], 0, 0, 0);
            accw[nt] = __builtin_amdgcn_mfma_f32_16x16x32_bf16(af, bw, accw[nt], 0, 0, 0);
        }
    }

    // ---- writeback (slot layout, paired dword stores) + rowv epilogue ----
    float bwv[2], qv[2];
#pragma unroll
    for (int nt = 0; nt < 2; ++nt) {
        const int col = n0 + nt * 16 + n16;
        bwv[nt] = bW3[col];
        qv[nt]  = q[col];
    }
    const int s = wv * 16 + n16;   // pair-slot: cols (n0+n16, n0+16+n16)
#pragma unroll
    for (int reg = 0; reg < 4; ++reg) {
        const int row = r0 + quad * 4 + reg;
        x4b[(size_t)row * 64 + s] = packbf2(acc4[0][reg], acc4[1][reg]);
        xwb[(size_t)row * 64 + s] = packbf2(accw[0][reg] + bwv[0],
                                            accw[1][reg] + bwv[1]);
    }
    float pr[4];
#pragma unroll
    for (int reg = 0; reg < 4; ++reg)
        pr[reg] = qv[0] * acc4[0][reg] + qv[1] * acc4[1][reg];
#pragma unroll
    for (int m = 8; m; m >>= 1) {
#pragma unroll
        for (int reg = 0; reg < 4; ++reg) pr[reg] += __shfl_xor(pr[reg], m, 64);
    }
    if (t < 16) srow[t] = 0.f;
    __syncthreads();
    if (n16 == 0) {
#pragma unroll
        for (int reg = 0; reg < 4; ++reg) atomicAdd(&srow[quad * 4 + reg], pr[reg]);
    }
    __syncthreads();
    if (t < 16) rowv[r0 + t] = srow[t] * TEMPR;
}

// ---------------------------------------------------------------------------
// K2: per-edge softmax1 -> Sval + ws scatter; bf16 gathers e4b / G1b.
// ---------------------------------------------------------------------------
__global__ __launch_bounds__(128, 4) void k_edge1(
    const int* __restrict__ degE, const int* __restrict__ csrEn,
    const float* __restrict__ rowv,
    const float* __restrict__ csx4, const float* __restrict__ csxw,
    const unsigned* __restrict__ x4b, const unsigned* __restrict__ xwb,
    float* __restrict__ Sval, unsigned* __restrict__ e4b, unsigned* __restrict__ G1b,
    float* __restrict__ wsArr)
{
    __shared__ int   sN[2][EC];
    __shared__ float sS[2][EC];
    const int t    = threadIdx.x;
    const int w    = t >> 6;
    const int lane = t & 63;
    const int e    = blockIdx.x * 2 + w;
    const int deg  = min(degE[e], EC);
    const float ue = deg ? 1.0f / ((float)Nn + (float)deg * EM1) : 2.0f / (float)Nn;

    int   n0 = 0, n1 = 0;
    float r0 = -INFINITY, r1 = -INFINITY;
    if (lane < deg)      { n0 = csrEn[e * EC + lane];      r0 = rowv[n0]; }
    if (lane + 64 < deg) { n1 = csrEn[e * EC + lane + 64]; r1 = rowv[n1]; }
    const float m  = wave_max64(fmaxf(r0, r1));
    const float e0 = (lane < deg)      ? expf(r0 - m) : 0.f;
    const float e1 = (lane + 64 < deg) ? expf(r1 - m) : 0.f;
    const float Z  = wave_sum64(e0 + e1);
    const float inv = deg ? 1.0f / Z : 0.f;
    const float base = EM1 * ue;
    if (lane < deg) {
        const float sv = fmaf(e0, inv, base);
        sN[w][lane] = n0; sS[w][lane] = sv;
        Sval[e * EC + lane] = sv;
        atomicAdd(&wsArr[n0], ue * sv);
    }
    if (lane + 64 < deg) {
        const float sv = fmaf(e1, inv, base);
        sN[w][lane + 64] = n1; sS[w][lane + 64] = sv;
        Sval[e * EC + lane + 64] = sv;
        atomicAdd(&wsArr[n1], ue * sv);
    }

    const float2 cw = *(const float2*)&csxw[lane * 2];
    const float2 c4 = *(const float2*)&csx4[lane * 2];
    float2 aE = make_float2(ue * cw.x, ue * cw.y);
    float2 aG = make_float2(ue * c4.x, ue * c4.y);
    int j = 0;
    for (; j + 16 <= deg; j += 16) {
        int ai[16]; float bi[16]; unsigned tu[16], fu[16];
#pragma unroll
        for (int k = 0; k < 16; ++k) { ai[k] = sN[w][j+k]; bi[k] = sS[w][j+k]; }
#pragma unroll
        for (int k = 0; k < 16; ++k) {
            tu[k] = xwb[(size_t)ai[k] * 64 + lane];
            fu[k] = x4b[(size_t)ai[k] * 64 + lane];
        }
#pragma unroll
        for (int k = 0; k < 16; ++k) {
            const float2 tv = unpackbf2(tu[k]);
            const float2 fv = unpackbf2(fu[k]);
            aE.x = fmaf(bi[k], tv.x, aE.x); aE.y = fmaf(bi[k], tv.y, aE.y);
            aG.x = fmaf(bi[k], fv.x, aG.x); aG.y = fmaf(bi[k], fv.y, aG.y);
        }
    }
    for (; j + 8 <= deg; j += 8) {
        int ai[8]; float bi[8]; unsigned tu[8], fu[8];
#pragma unroll
        for (int k = 0; k < 8; ++k) { ai[k] = sN[w][j+k]; bi[k] = sS[w][j+k]; }
#pragma unroll
        for (int k = 0; k < 8; ++k) {
            tu[k] = xwb[(size_t)ai[k] * 64 + lane];
            fu[k] = x4b[(size_t)ai[k] * 64 + lane];
        }
#pragma unroll
        for (int k = 0; k < 8; ++k) {
            const float2 tv = unpackbf2(tu[k]);
            const float2 fv = unpackbf2(fu[k]);
            aE.x = fmaf(bi[k], tv.x, aE.x); aE.y = fmaf(bi[k], tv.y, aE.y);
            aG.x = fmaf(bi[k], fv.x, aG.x); aG.y = fmaf(bi[k], fv.y, aG.y);
        }
    }
    for (; j < deg; ++j) {
        const int   a = sN[w][j];
        const float b = sS[w][j];
        const float2 tv = unpackbf2(xwb[(size_t)a * 64 + lane]);
        const float2 fv = unpackbf2(x4b[(size_t)a * 64 + lane]);
        aE.x = fmaf(b, tv.x, aE.x); aE.y = fmaf(b, tv.y, aE.y);
        aG.x = fmaf(b, fv.x, aG.x); aG.y = fmaf(b, fv.y, aG.y);
    }
    e4b[(size_t)e * 64 + lane] = packbf2(aE.x, aE.y);
    G1b[(size_t)e * 64 + lane] = packbf2(aG.x, aG.y);
}

// ---------------------------------------------------------------------------
// K3: merged. Blocks 0..63: weighted colsums (vn/tw/ws on x4b) -> vxg/twg/
//     wsg + c2g. Blocks 64..: per-node softmax2 -> Tval.
// ---------------------------------------------------------------------------
__global__ __launch_bounds__(256) void k_nodeB(
    const int* __restrict__ degN, const int* __restrict__ degE,
    const int* __restrict__ csrNe,
    const int* __restrict__ csrNs, const unsigned* __restrict__ x4b,
    const unsigned* __restrict__ e4b, const float* __restrict__ wsArr,
    float* __restrict__ Tval,
    float* __restrict__ vxg, float* __restrict__ twg, float* __restrict__ wsg,
    float* __restrict__ c2g)
{
    const int t    = threadIdx.x;
    const int w    = t >> 6;
    const int lane = t & 63;
    const int b    = blockIdx.x;

    if (b < 64) {                         // ---- redux part ----
        float2 av = {0.f, 0.f}, at2 = {0.f, 0.f}, aw = {0.f, 0.f};
        for (int k = 0; k < 32; ++k) {
            const int n   = b * 128 + w + k * 4;
            const int deg = min(degN[n], NC);
            const float vn = deg ? 1.0f / ((float)Ee + (float)deg * EM1)
                                 : 2.0f / (float)Ee;
            const float tw = deg ? fmaf((float)deg * EM1, vn, 1.0f) : 0.f;
            const float wsn = wsArr[n];
            const float2 xv = unpackbf2(x4b[(size_t)n * 64 + lane]);
            av.x  = fmaf(vn,  xv.x, av.x);  av.y  = fmaf(vn,  xv.y, av.y);
            at2.x = fmaf(tw,  xv.x, at2.x); at2.y = fmaf(tw,  xv.y, at2.y);
            aw.x  = fmaf(wsn, xv.x, aw.x);  aw.y  = fmaf(wsn, xv.y, aw.y);
        }
        atomicAdd(&vxg[lane*2+0], av.x);  atomicAdd(&vxg[lane*2+1], av.y);
        atomicAdd(&twg[lane*2+0], at2.x); atomicAdd(&twg[lane*2+1], at2.y);
        atomicAdd(&wsg[lane*2+0], aw.x);  atomicAdd(&wsg[lane*2+1], aw.y);
        // ---- c2g (edges 0..4095 in blocks 0..15) ----
        const int gid = b * 256 + t;
        if (gid < Ee) {
            const int de = min(degE[gid], EC);
            const float ue = de ? 1.0f / ((float)Nn + (float)de * EM1)
                                : 2.0f / (float)Nn;
            const float v = wave_sum64(ue * ue);
            if (lane == 0) atomicAdd(c2g, v);
        }
        return;
    }

    // ---- node2 part ----
    const int es   = lane >> 3;           // edge slot within pass (0..7)
    const int dl   = lane & 7;            // dim-lane
    const int n    = (b - 64) * 4 + w;    // one node per wave
    const int deg  = min(degN[n], NC);
    if (!deg) return;                     // wave-uniform
    const float vn = 1.0f / ((float)Ee + (float)deg * EM1);

    const uint4* xr = (const uint4*)&x4b[(size_t)n * 64];
    const uint4 xua = xr[dl * 2], xub = xr[dl * 2 + 1];
    const float2 x0 = unpackbf2(xua.x), x1 = unpackbf2(xua.y),
                 x2 = unpackbf2(xua.z), x3 = unpackbf2(xua.w),
                 x4v = unpackbf2(xub.x), x5 = unpackbf2(xub.y),
                 x6 = unpackbf2(xub.z), x7 = unpackbf2(xub.w);

    float dps[6]; float exs[6]; int slots[6];
    float m = -INFINITY;
#pragma unroll
    for (int p = 0; p < 6; ++p) {
        dps[p] = -INFINITY; slots[p] = 0;
        if (p * 8 >= deg) continue;       // wave-uniform branch
        const int j = p * 8 + es;
        int ej = 0;
        if (j < deg) { ej = csrNe[n * NC + j]; slots[p] = csrNs[n * NC + j]; }
        const uint4* er = (const uint4*)&e4b[(size_t)ej * 64];
        const uint4 ea = er[dl * 2], eb = er[dl * 2 + 1];
        float d0 = 0.f, d1 = 0.f, d2 = 0.f, d3 = 0.f;
        { const float2 ev = unpackbf2(ea.x); d0 = fmaf(ev.x, x0.x, d0); d0 = fmaf(ev.y, x0.y, d0); }
        { const float2 ev = unpackbf2(ea.y); d1 = fmaf(ev.x, x1.x, d1); d1 = fmaf(ev.y, x1.y, d1); }
        { const float2 ev = unpackbf2(ea.z); d2 = fmaf(ev.x, x2.x, d2); d2 = fmaf(ev.y, x2.y, d2); }
        { const float2 ev = unpackbf2(ea.w); d3 = fmaf(ev.x, x3.x, d3); d3 = fmaf(ev.y, x3.y, d3); }
        { const float2 ev = unpackbf2(eb.x); d0 = fmaf(ev.x, x4v.x, d0); d0 = fmaf(ev.y, x4v.y, d0); }
        { const float2 ev = unpackbf2(eb.y); d1 = fmaf(ev.x, x5.x, d1); d1 = fmaf(ev.y, x5.y, d1); }
        { const float2 ev = unpackbf2(eb.z); d2 = fmaf(ev.x, x6.x, d2); d2 = fmaf(ev.y, x6.y, d2); }
        { const float2 ev = unpackbf2(eb.w); d3 = fmaf(ev.x, x7.x, d3); d3 = fmaf(ev.y, x7.y, d3); }
        float dot = (d0 + d1) + (d2 + d3);
        dot += __shfl_xor(dot, 1, 64);
        dot += __shfl_xor(dot, 2, 64);
        dot += __shfl_xor(dot, 4, 64);
        dot = (j < deg) ? dot * TEMPR : -INFINITY;
        dps[p] = dot;
        float mm = fmaxf(dot, __shfl_xor(dot, 8, 64));
        mm = fmaxf(mm, __shfl_xor(mm, 16, 64));
        mm = fmaxf(mm, __shfl_xor(mm, 32, 64));
        m = fmaxf(m, mm);
    }
    float Z = 0.f;
#pragma unroll
    for (int p = 0; p < 6; ++p) {
        exs[p] = 0.f;
        if (p * 8 >= deg) continue;
        const float ex = (p * 8 + es < deg) ? expf(dps[p] - m) : 0.f;
        exs[p] = ex;
        float sum = ex + __shfl_xor(ex, 8, 64);
        sum += __shfl_xor(sum, 16, 64);
        sum += __shfl_xor(sum, 32, 64);
        Z += sum;
    }
    const float invZ = 1.0f / Z;
#pragma unroll
    for (int p = 0; p < 6; ++p) {
        if (p * 8 >= deg) continue;
        if (dl == 0 && p * 8 + es < deg)
            Tval[slots[p]] = fmaf(EM1, vn, exs[p] * invZ);
    }
}

// ---------------------------------------------------------------------------
// K4: per-edge: G2b[e] = vx + sum_{n in e} T[e,n] * x4[n].
// ---------------------------------------------------------------------------
__global__ __launch_bounds__(128, 4) void k_g2(
    const int* __restrict__ degE, const int* __restrict__ csrEn,
    const float* __restrict__ Tval, const float* __restrict__ vxg,
    const unsigned* __restrict__ x4b, unsigned* __restrict__ G2b)
{
    const int t    = threadIdx.x;
    const int w    = t >> 6;
    const int lane = t & 63;
    const int e    = blockIdx.x * 2 + w;
    const int deg  = min(degE[e], EC);
    float2 acc = *(const float2*)&vxg[lane * 2];
    int j = 0;
    for (; j + 16 <= deg; j += 16) {
        int ai[16]; float bi[16]; unsigned fu[16];
#pragma unroll
        for (int k = 0; k < 16; ++k) { ai[k] = csrEn[e*EC+j+k]; bi[k] = Tval[e*EC+j+k]; }
#pragma unroll
        for (int k = 0; k < 16; ++k)
            fu[k] = x4b[(size_t)ai[k] * 64 + lane];
#pragma unroll
        for (int k = 0; k < 16; ++k) {
            const float2 fv = unpackbf2(fu[k]);
            acc.x = fmaf(bi[k], fv.x, acc.x); acc.y = fmaf(bi[k], fv.y, acc.y);
        }
    }
    for (; j + 8 <= deg; j += 8) {
        int ai[8]; float bi[8]; unsigned fu[8];
#pragma unroll
        for (int k = 0; k < 8; ++k) { ai[k] = csrEn[e*EC+j+k]; bi[k] = Tval[e*EC+j+k]; }
#pragma unroll
        for (int k = 0; k < 8; ++k)
            fu[k] = x4b[(size_t)ai[k] * 64 + lane];
#pragma unroll
        for (int k = 0; k < 8; ++k) {
            const float2 fv = unpackbf2(fu[k]);
            acc.x = fmaf(bi[k], fv.x, acc.x); acc.y = fmaf(bi[k], fv.y, acc.y);
        }
    }
    for (; j < deg; ++j) {
        const int   a = csrEn[e*EC+j];
        const float b = Tval[e*EC+j];
        const float2 fv = unpackbf2(x4b[(size_t)a * 64 + lane]);
        acc.x = fmaf(b, fv.x, acc.x); acc.y = fmaf(b, fv.y, acc.y);
    }
    G2b[(size_t)e * 64 + lane] = packbf2(acc.x, acc.y);
}

// ---------------------------------------------------------------------------
// K5: final per-node combine + elu.  Unscrambles slot layout.
// ---------------------------------------------------------------------------
__global__ __launch_bounds__(128, 4) void k_final(
    const int* __restrict__ degN, const int* __restrict__ csrNe,
    const int* __restrict__ csrNs, const float* __restrict__ Sval,
    const float* __restrict__ Tval,
    const float* __restrict__ c2g, const float* __restrict__ csx4,
    const float* __restrict__ wsg, const float* __restrict__ vxg,
    const float* __restrict__ twg,
    const unsigned* __restrict__ G1b, const unsigned* __restrict__ G2b,
    float* __restrict__ out)
{
    const int t    = threadIdx.x;
    const int w    = t >> 6;
    const int lane = t & 63;
    const int n    = blockIdx.x * 2 + w;
    const int deg  = min(degN[n], NC);
    const float vn = deg ? 1.0f / ((float)Ee + (float)deg * EM1) : 2.0f / (float)Ee;
    const float c2 = *c2g;
    const float2 c4v = *(const float2*)&csx4[lane * 2];
    const float2 wsv = *(const float2*)&wsg[lane * 2];
    const float2 vxv = *(const float2*)&vxg[lane * 2];
    const float2 twv = *(const float2*)&twg[lane * 2];
    float2 acc;
    acc.x = fmaf(c2, c4v.x, wsv.x) + vn * fmaf((float)Ee, vxv.x, twv.x);
    acc.y = fmaf(c2, c4v.y, wsv.y) + vn * fmaf((float)Ee, vxv.y, twv.y);
    int j = 0;
    for (; j + 8 <= deg; j += 8) {
        int ei[8], si[8]; float sv[8], tv[8]; unsigned g1u[8], g2u[8];
#pragma unroll
        for (int k = 0; k < 8; ++k) {
            ei[k] = csrNe[n*NC+j+k]; si[k] = csrNs[n*NC+j+k];
        }
#pragma unroll
        for (int k = 0; k < 8; ++k) {
            sv[k] = Sval[si[k]]; tv[k] = Tval[si[k]];
            g1u[k] = G1b[(size_t)ei[k] * 64 + lane];
            g2u[k] = G2b[(size_t)ei[k] * 64 + lane];
        }
#pragma unroll
        for (int k = 0; k < 8; ++k) {
            const float2 g1 = unpackbf2(g1u[k]);
            const float2 g2 = unpackbf2(g2u[k]);
            acc.x = fmaf(sv[k], g1.x, acc.x); acc.y = fmaf(sv[k], g1.y, acc.y);
            acc.x = fmaf(tv[k], g2.x, acc.x); acc.y = fmaf(tv[k], g2.y, acc.y);
        }
    }
    for (; j + 4 <= deg; j += 4) {
        int ei[4], si[4]; float sv[4], tv[4]; unsigned g1u[4], g2u[4];
#pragma unroll
        for (int k = 0; k < 4; ++k) {
            ei[k] = csrNe[n*NC+j+k]; si[k] = csrNs[n*NC+j+k];
        }
#pragma unroll
        for (int k = 0; k < 4; ++k) {
            sv[k] = Sval[si[k]]; tv[k] = Tval[si[k]];
            g1u[k] = G1b[(size_t)ei[k] * 64 + lane];
            g2u[k] = G2b[(size_t)ei[k] * 64 + lane];
        }
#pragma unroll
        for (int k = 0; k < 4; ++k) {
            const float2 g1 = unpackbf2(g1u[k]);
            const float2 g2 = unpackbf2(g2u[k]);
            acc.x = fmaf(sv[k], g1.x, acc.x); acc.y = fmaf(sv[k], g1.y, acc.y);
            acc.x = fmaf(tv[k], g2.x, acc.x); acc.y = fmaf(tv[k], g2.y, acc.y);
        }
    }
    for (; j < deg; ++j) {
        const int ea = csrNe[n*NC+j];
        const int sa = csrNs[n*NC+j];
        const float sva = Sval[sa], tva = Tval[sa];
        const float2 g1a = unpackbf2(G1b[(size_t)ea * 64 + lane]);
        const float2 g2a = unpackbf2(G2b[(size_t)ea * 64 + lane]);
        acc.x = fmaf(sva, g1a.x, acc.x); acc.y = fmaf(sva, g1a.y, acc.y);
        acc.x = fmaf(tva, g2a.x, acc.x); acc.y = fmaf(tva, g2a.y, acc.y);
    }
    acc.x = acc.x > 0.f ? acc.x : expm1f(acc.x);
    acc.y = acc.y > 0.f ? acc.y : expm1f(acc.y);
    // unscramble slot layout: slot holds dims lo and lo+16
    const int lo = ((lane >> 4) << 5) + (lane & 15);
    out[(size_t)n * DOUT + lo]      = acc.x;
    out[(size_t)n * DOUT + lo + 16] = acc.y;
}

// ---------------------------------------------------------------------------
extern "C" void kernel_launch(void* const* d_in, const int* in_sizes, int n_in,
                              void* d_out, int out_size, void* d_ws, size_t ws_size,
                              hipStream_t stream)
{
    const float* x    = (const float*)d_in[0];
    const float* W    = (const float*)d_in[1];
    const float* W2   = (const float*)d_in[2];
    const float* W3   = (const float*)d_in[3];
    const float* bias = (const float*)d_in[4];
    const float* q    = (const float*)d_in[5];
    const int*   hidx = (const int*)d_in[6];
    float* out = (float*)d_out;

    char* wsp = (char*)d_ws;
    size_t o = 0;
    auto take = [&](size_t bytes) {
        size_t r = o; o += (bytes + 255) & ~(size_t)255; return r;
    };
    // --- zero-initialized region (zeroed by k_ww3 blocks 41..168) ---
    unsigned* bitmap = (unsigned*)(wsp + take((size_t)Nn * Ee / 8));   // 4 MB
    int*   degE  = (int*)  (wsp + take((size_t)Ee * 4));
    int*   degN  = (int*)  (wsp + take((size_t)Nn * 4));
    float* wsArr = (float*)(wsp + take((size_t)Nn * 4));
    float* c2g   = (float*)(wsp + take(4));
    float* vxg   = (float*)(wsp + take(DOUT * 4));
    float* twg   = (float*)(wsp + take(DOUT * 4));
    float* wsg   = (float*)(wsp + take(DOUT * 4));
    const size_t zbytes = o;
    // --- fully-overwritten scratch ---
    float*    csx4  = (float*)   (wsp + take(DOUT * 4));
    float*    csxw  = (float*)   (wsp + take(DOUT * 4));
    float*    sxPart= (float*)   (wsp + take(128 * 256 * 4));         // 128 KB
    short*    xb    = (short*)   (wsp + take((size_t)Nn * DIN * 2));  // 4 MB bf16 x
    unsigned* x4b   = (unsigned*)(wsp + take((size_t)Nn * 64 * 4));   // bf16 pairs
    unsigned* xwb   = (unsigned*)(wsp + take((size_t)Nn * 64 * 4));   // bf16 pairs
    float*    rowv  = (float*)   (wsp + take((size_t)Nn * 4));
    int*      csrEn = (int*)     (wsp + take((size_t)Ee * EC * 4));
    float*    Sval  = (float*)   (wsp + take((size_t)Ee * EC * 4));
    float*    Tval  = (float*)   (wsp + take((size_t)Ee * EC * 4));
    int*      csrNe = (int*)     (wsp + take((size_t)Nn * NC * 4));
    int*      csrNs = (int*)     (wsp + take((size_t)Nn * NC * 4));
    unsigned* e4b   = (unsigned*)(wsp + take((size_t)Ee * 64 * 4));   // bf16 pairs
    unsigned* G1b   = (unsigned*)(wsp + take((size_t)Ee * 64 * 4));   // bf16 pairs
    unsigned* G2b   = (unsigned*)(wsp + take((size_t)Ee * 64 * 4));   // bf16 pairs
    short*    W2T   = (short*)   (wsp + take((size_t)DOUT * DIN * 2));
    short*    WWT   = (short*)   (wsp + take((size_t)DOUT * DIN * 2));
    float*    bW3   = (float*)   (wsp + take(DOUT * 4));
    (void)ws_size; (void)in_sizes; (void)n_in; (void)out_size;

    k_ww3   <<<169,          256, 0, stream>>>(x, W, W2, W3, bias, W2T, WWT, bW3,
                                               sxPart, (uint2*)xb, (uint4*)d_ws,
                                               (unsigned)(zbytes / 16));
    k_gemm1f<<<513,          256, 0, stream>>>(xb, W2T, WWT, bW3, q, hidx, sxPart,
                                               bitmap, degE, degN, csrEn, csrNe,
                                               csrNs, x4b, xwb, rowv, csx4, csxw);
    k_edge1 <<<Ee / 2,       128, 0, stream>>>(degE, csrEn, rowv, csx4, csxw,
                                               x4b, xwb, Sval, e4b, G1b, wsArr);
    k_nodeB <<<64 + Nn / 4,  256, 0, stream>>>(degN, degE, csrNe, csrNs, x4b, e4b,
                                               wsArr, Tval, vxg, twg, wsg, c2g);
    k_g2    <<<Ee / 2,       128, 0, stream>>>(degE, csrEn, Tval, vxg, x4b, G2b);
    k_final <<<Nn / 2,       128, 0, stream>>>(degN, csrNe, csrNs, Sval, Tval,
                                               c2g, csx4, wsg, vxg, twg, G1b, G2b,
                                               out);
}